// Round 2
// baseline (176.746 us; speedup 1.0000x reference)
//
#include <hip/hip_runtime.h>
#include <hip/hip_bf16.h>

#define NROWS 4096
#define IN_F 512
#define OUT_F 128
#define NBINS 128
#define NCLS 16
#define SIGMA 0.2f
#define EPSV 1e-8f
#define TAUV 0.1f
#define RPB 8   // rows per block in proj

#if defined(__has_builtin)
#if __has_builtin(__builtin_amdgcn_exp2f)
#define EXP2F(x) __builtin_amdgcn_exp2f(x)
#else
#define EXP2F(x) exp2f(x)
#endif
#else
#define EXP2F(x) exp2f(x)
#endif

// -0.5 / sigma^2 * log2(e)
#define C2EXP (-18.0336880f)

// ---------------- K1: MLP projection, 8 rows per block ----------------
// x reads are wave-uniform (scalar path); W reads coalesced per-lane.
__global__ __launch_bounds__(128) void proj_kernel(
    const float* __restrict__ X1, const float* __restrict__ X2,
    const float* __restrict__ W1, const float* __restrict__ b1,
    const float* __restrict__ W2, const float* __restrict__ b2,
    float* __restrict__ P)
{
    __shared__ float hs[RPB][OUT_F];
    const int f = threadIdx.x;
    const int row0 = blockIdx.x * RPB;            // global row in [0, 8192)
    const float* __restrict__ X = (row0 < NROWS) ? X1 : X2;
    const int xr0 = (row0 < NROWS) ? row0 : row0 - NROWS;

    float acc[RPB];
    #pragma unroll
    for (int r = 0; r < RPB; ++r) acc[r] = 0.f;

    for (int k = 0; k < IN_F; k += 4) {
        float w0 = W1[(k + 0) * OUT_F + f];
        float w1 = W1[(k + 1) * OUT_F + f];
        float w2 = W1[(k + 2) * OUT_F + f];
        float w3 = W1[(k + 3) * OUT_F + f];
        #pragma unroll
        for (int r = 0; r < RPB; ++r) {
            const float4 xv = *reinterpret_cast<const float4*>(
                X + (size_t)(xr0 + r) * IN_F + k);     // uniform -> s_load
            acc[r] = fmaf(xv.x, w0, acc[r]);
            acc[r] = fmaf(xv.y, w1, acc[r]);
            acc[r] = fmaf(xv.z, w2, acc[r]);
            acc[r] = fmaf(xv.w, w3, acc[r]);
        }
    }
    {
        float bb = b1[f];
        #pragma unroll
        for (int r = 0; r < RPB; ++r) hs[r][f] = fmaxf(acc[r] + bb, 0.f);
    }
    __syncthreads();

    float a2[RPB];
    #pragma unroll
    for (int r = 0; r < RPB; ++r) a2[r] = 0.f;

    for (int k = 0; k < OUT_F; k += 4) {
        float w0 = W2[(k + 0) * OUT_F + f];
        float w1 = W2[(k + 1) * OUT_F + f];
        float w2 = W2[(k + 2) * OUT_F + f];
        float w3 = W2[(k + 3) * OUT_F + f];
        #pragma unroll
        for (int r = 0; r < RPB; ++r) {
            const float4 hv = *reinterpret_cast<const float4*>(&hs[r][k]); // broadcast b128
            a2[r] = fmaf(hv.x, w0, a2[r]);
            a2[r] = fmaf(hv.y, w1, a2[r]);
            a2[r] = fmaf(hv.z, w2, a2[r]);
            a2[r] = fmaf(hv.w, w3, a2[r]);
        }
    }
    {
        float bb = b2[f];
        #pragma unroll
        for (int r = 0; r < RPB; ++r)
            P[(size_t)(row0 + r) * OUT_F + f] = a2[r] + bb;
    }
}

// ---------------- reductions over a 128-thread block (2 waves) ----------------
__device__ __forceinline__ float red_sum128(float v, float* red, int tid)
{
    #pragma unroll
    for (int off = 32; off; off >>= 1) v += __shfl_down(v, off);
    __syncthreads();
    if ((tid & 63) == 0) red[tid >> 6] = v;
    __syncthreads();
    return red[0] + red[1];
}

__device__ __forceinline__ float red_max128(float v, float* red, int tid)
{
    #pragma unroll
    for (int off = 32; off; off >>= 1) v = fmaxf(v, __shfl_down(v, off));
    __syncthreads();
    if ((tid & 63) == 0) red[tid >> 6] = v;
    __syncthreads();
    return fmaxf(red[0], red[1]);
}

// ---------------- K2: normalize + KDE pdf + softmax + segment accumulate ----------------
__global__ __launch_bounds__(128) void pdf_kernel(
    const float* __restrict__ P, const int* __restrict__ Y1, const int* __restrict__ Y2,
    const float* __restrict__ bins, float* __restrict__ dist, float* __restrict__ counts)
{
    __shared__ float4 xn4[OUT_F / 4];
    __shared__ float red[2];
    float* xn = (float*)xn4;
    const int j = threadIdx.x;
    const int row = blockIdx.x;            // 0..8191
    const int batch = row >> 12;           // row / 4096
    const int lrow = row & 4095;

    float p = P[(size_t)row * OUT_F + j];
    float nrm2 = red_sum128(p * p, red, j);
    float inv = 1.0f / sqrtf(nrm2);
    xn[j] = p * inv;
    __syncthreads();

    const float bj = bins[j];
    float acc = 0.f;
    #pragma unroll 8
    for (int q = 0; q < OUT_F / 4; ++q) {
        float4 v = xn4[q];                 // broadcast ds_read_b128
        float t0 = v.x - bj;
        float t1 = v.y - bj;
        float t2 = v.z - bj;
        float t3 = v.w - bj;
        acc += EXP2F(C2EXP * t0 * t0);
        acc += EXP2F(C2EXP * t1 * t1);
        acc += EXP2F(C2EXP * t2 * t2);
        acc += EXP2F(C2EXP * t3 * t3);
    }
    float pdf = acc * (1.0f / OUT_F);

    float s = red_sum128(pdf, red, j);
    pdf = pdf / (s + EPSV);

    float m = red_max128(pdf, red, j);
    float e = __expf(pdf - m);
    float es = red_sum128(e, red, j);
    float sm = e / es;

    int cls = (batch == 0 ? Y1 : Y2)[lrow];
    atomicAdd(&dist[(size_t)(batch * NCLS + cls) * NBINS + j], sm);
    if (j == 0) atomicAdd(&counts[batch * NCLS + cls], 1.0f);
}

// ---------------- K3: class means, KL matrix, loss ----------------
__global__ __launch_bounds__(256) void final_kernel(
    const float* __restrict__ dist, const float* __restrict__ counts,
    float* __restrict__ out)
{
    __shared__ float PA[32][NBINS], LA[32][NBINS];
    __shared__ float PB[32][NBINS], LB[32][NBINS];
    __shared__ float J[32][32];
    __shared__ float pls[32];
    const int tid = threadIdx.x;

    for (int idx = tid; idx < NCLS * NBINS; idx += 256) {
        int c = idx >> 7, j = idx & 127;
        float a = dist[idx] / counts[c];
        float b = dist[NCLS * NBINS + idx] / counts[NCLS + c];
        float mm = 0.5f * (a + b);
        PA[c][j] = a;       LA[c][j] = logf(a);
        PA[c + 16][j] = mm; LA[c + 16][j] = logf(mm);
        PB[c][j] = b;       LB[c][j] = logf(b);
        PB[c + 16][j] = mm; LB[c + 16][j] = logf(mm);
    }
    __syncthreads();

    for (int pair = tid; pair < 32 * 32; pair += 256) {
        int i = pair >> 5, k = pair & 31;
        if (i == k) { J[i][k] = 0.f; continue; }
        float sA = 0.f, sB = 0.f;
        for (int jj = 0; jj < NBINS; ++jj) {
            sA += PA[i][jj] * (LA[i][jj] - LA[k][jj]);
            sB += PB[i][jj] * (LB[i][jj] - LB[k][jj]);
        }
        J[i][k] = 0.5f * (sA + sB);
    }
    __syncthreads();

    if (tid < 32) {
        float den = 0.f;
        for (int k = 0; k < 32; ++k) den += __expf(J[tid][k] * (1.0f / TAUV));
        float pos = J[tid][(tid + 16) & 31];
        pls[tid] = -(pos * (1.0f / TAUV)) + logf(den);
    }
    __syncthreads();
    if (tid == 0) {
        float s = 0.f;
        for (int i = 0; i < 32; ++i) s += pls[i];
        out[0] = s * (1.0f / 32.0f);
    }
}

extern "C" void kernel_launch(void* const* d_in, const int* in_sizes, int n_in,
                              void* d_out, int out_size, void* d_ws, size_t ws_size,
                              hipStream_t stream)
{
    const float* x1   = (const float*)d_in[0];
    const int*   y1   = (const int*)d_in[1];
    const float* x2   = (const float*)d_in[2];
    const int*   y2   = (const int*)d_in[3];
    const float* W1   = (const float*)d_in[4];
    const float* b1   = (const float*)d_in[5];
    const float* W2   = (const float*)d_in[6];
    const float* b2   = (const float*)d_in[7];
    const float* bins = (const float*)d_in[8];
    float* out = (float*)d_out;

    char* ws = (char*)d_ws;
    float* P      = (float*)ws;                                        // 8192*128 floats
    float* dist   = (float*)(ws + (size_t)8192 * 128 * sizeof(float)); // 2*16*128
    float* counts = dist + 2 * NCLS * NBINS;                           // 2*16

    hipMemsetAsync(dist, 0, (2 * NCLS * NBINS + 2 * NCLS) * sizeof(float), stream);

    proj_kernel<<<8192 / RPB, 128, 0, stream>>>(x1, x2, W1, b1, W2, b2, P);
    pdf_kernel<<<8192, 128, 0, stream>>>(P, y1, y2, bins, dist, counts);
    final_kernel<<<1, 256, 0, stream>>>(dist, counts, out);
}

// Round 3
// 154.332 us; speedup vs baseline: 1.1452x; 1.1452x over previous
//
#include <hip/hip_runtime.h>
#include <hip/hip_bf16.h>

#define NROWS 4096
#define IN_F 512
#define OUT_F 128
#define NBINS 128
#define NCLS 16
#define EPSV 1e-8f
#define TAUV 0.1f

// -0.5 / sigma^2 * log2(e),  sigma = 0.2
#define C2EXP (-18.0336880f)

#if defined(__has_builtin)
#if __has_builtin(__builtin_amdgcn_exp2f)
#define EXP2F(x) __builtin_amdgcn_exp2f(x)
#else
#define EXP2F(x) exp2f(x)
#endif
#else
#define EXP2F(x) exp2f(x)
#endif

typedef __attribute__((ext_vector_type(8))) short bf16x8;
typedef __attribute__((ext_vector_type(4))) float f32x4;

__device__ __forceinline__ short cvt_bf16(float x) {
    __hip_bfloat16 h = __float2bfloat16(x);
    return *reinterpret_cast<short*>(&h);
}

// ---------------- K0: transpose + convert weights to bf16 ----------------
__global__ __launch_bounds__(128) void prep_w(
    const float* __restrict__ W1, const float* __restrict__ W2,
    __hip_bfloat16* __restrict__ W1T, __hip_bfloat16* __restrict__ W2T)
{
    const int n = blockIdx.x;      // 0..127 output row (= original col)
    const int t = threadIdx.x;
    for (int k = t; k < IN_F; k += 128)
        W1T[(size_t)n * IN_F + k] = __float2bfloat16(W1[(size_t)k * OUT_F + n]);
    W2T[(size_t)n * OUT_F + t] = __float2bfloat16(W2[(size_t)t * OUT_F + n]);
}

// ---------------- K1: fused MLP projection via bf16 MFMA ----------------
// block = 512 thr = 8 waves; 16 rows/block; wave w owns col tile [16w,16w+16)
__global__ __launch_bounds__(512) void proj_mfma(
    const float* __restrict__ X1, const float* __restrict__ X2,
    const __hip_bfloat16* __restrict__ W1T, const float* __restrict__ b1,
    const __hip_bfloat16* __restrict__ W2T, const float* __restrict__ b2,
    float* __restrict__ P)
{
    __shared__ __hip_bfloat16 h_lds[16][136];   // +8 bf16 pad: 16B-aligned rows, 2-way banks
    const int tid  = threadIdx.x;
    const int wave = tid >> 6;
    const int lane = tid & 63;
    const int lr   = lane & 15;     // M index (A) / N index (B)
    const int kg   = lane >> 4;     // k-group 0..3 (8 bf16 each)
    const int row0 = blockIdx.x * 16;
    const float* __restrict__ X = (row0 < NROWS) ? X1 : X2;
    const int xr0 = (row0 < NROWS) ? row0 : row0 - NROWS;
    const int col = wave * 16 + lr;

    // ---- GEMM1: (16 x 512) * (512 x 128), K-loop of 32 ----
    f32x4 acc = {0.f, 0.f, 0.f, 0.f};
    const float* __restrict__ xrow = X + (size_t)(xr0 + lr) * IN_F;
    const __hip_bfloat16* __restrict__ wrow = W1T + (size_t)col * IN_F;
    #pragma unroll 4
    for (int ks = 0; ks < IN_F / 32; ++ks) {
        const int kb = ks * 32 + kg * 8;
        float4 v0 = *reinterpret_cast<const float4*>(xrow + kb);
        float4 v1 = *reinterpret_cast<const float4*>(xrow + kb + 4);
        bf16x8 a;
        a[0] = cvt_bf16(v0.x); a[1] = cvt_bf16(v0.y);
        a[2] = cvt_bf16(v0.z); a[3] = cvt_bf16(v0.w);
        a[4] = cvt_bf16(v1.x); a[5] = cvt_bf16(v1.y);
        a[6] = cvt_bf16(v1.z); a[7] = cvt_bf16(v1.w);
        bf16x8 b = *reinterpret_cast<const bf16x8*>(wrow + kb);
        acc = __builtin_amdgcn_mfma_f32_16x16x32_bf16(a, b, acc, 0, 0, 0);
    }

    // relu + bias -> h_lds (bf16)
    {
        const float bb = b1[col];
        #pragma unroll
        for (int q = 0; q < 4; ++q) {
            float hv = fmaxf(acc[q] + bb, 0.f);
            h_lds[kg * 4 + q][col] = __float2bfloat16(hv);
        }
    }
    __syncthreads();

    // ---- GEMM2: (16 x 128) * (128 x 128) ----
    f32x4 acc2 = {0.f, 0.f, 0.f, 0.f};
    const __hip_bfloat16* __restrict__ w2row = W2T + (size_t)col * OUT_F;
    #pragma unroll
    for (int ks = 0; ks < OUT_F / 32; ++ks) {
        const int kb = ks * 32 + kg * 8;
        bf16x8 a2 = *reinterpret_cast<const bf16x8*>(&h_lds[lr][kb]);
        bf16x8 b2f = *reinterpret_cast<const bf16x8*>(w2row + kb);
        acc2 = __builtin_amdgcn_mfma_f32_16x16x32_bf16(a2, b2f, acc2, 0, 0, 0);
    }
    {
        const float bb2 = b2[col];
        #pragma unroll
        for (int q = 0; q < 4; ++q)
            P[(size_t)(row0 + kg * 4 + q) * OUT_F + col] = acc2[q] + bb2;
    }
}

// ---------------- K2: one wave per row: normalize + KDE + softmax + atomics ----------------
__global__ __launch_bounds__(256) void pdf_kernel(
    const float* __restrict__ P, const int* __restrict__ Y1, const int* __restrict__ Y2,
    const float* __restrict__ bins, float* __restrict__ dist, float* __restrict__ counts)
{
    const int wave = threadIdx.x >> 6;
    const int lane = threadIdx.x & 63;
    const int row  = blockIdx.x * 4 + wave;   // 0..8191
    const int batch = row >> 12;
    const int lrow  = row & 4095;

    float p0 = P[(size_t)row * OUT_F + lane];
    float p1 = P[(size_t)row * OUT_F + 64 + lane];

    float ss = p0 * p0 + p1 * p1;
    #pragma unroll
    for (int off = 32; off; off >>= 1) ss += __shfl_xor(ss, off);
    const float inv = 1.0f / sqrtf(ss);
    const float xn0 = p0 * inv, xn1 = p1 * inv;

    const float bj0 = bins[lane], bj1 = bins[lane + 64];
    float acc0 = 0.f, acc1 = 0.f;
    #pragma unroll 8
    for (int d = 0; d < 64; ++d) {
        const float xd = __shfl(xn0, d);
        const float t0 = xd - bj0, t1 = xd - bj1;
        acc0 += EXP2F(C2EXP * t0 * t0);
        acc1 += EXP2F(C2EXP * t1 * t1);
    }
    #pragma unroll 8
    for (int d = 0; d < 64; ++d) {
        const float xd = __shfl(xn1, d);
        const float t0 = xd - bj0, t1 = xd - bj1;
        acc0 += EXP2F(C2EXP * t0 * t0);
        acc1 += EXP2F(C2EXP * t1 * t1);
    }

    float pdf0 = acc0 * (1.0f / OUT_F), pdf1 = acc1 * (1.0f / OUT_F);
    float s = pdf0 + pdf1;
    #pragma unroll
    for (int off = 32; off; off >>= 1) s += __shfl_xor(s, off);
    const float rs = 1.0f / (s + EPSV);
    pdf0 *= rs; pdf1 *= rs;

    float m = fmaxf(pdf0, pdf1);
    #pragma unroll
    for (int off = 32; off; off >>= 1) m = fmaxf(m, __shfl_xor(m, off));
    const float e0 = __expf(pdf0 - m), e1 = __expf(pdf1 - m);
    float es = e0 + e1;
    #pragma unroll
    for (int off = 32; off; off >>= 1) es += __shfl_xor(es, off);
    const float r = 1.0f / es;

    const int cls = (batch ? Y2 : Y1)[lrow];
    float* dp = &dist[(size_t)(batch * NCLS + cls) * NBINS];
    atomicAdd(dp + lane, e0 * r);
    atomicAdd(dp + lane + 64, e1 * r);
    if (lane == 0) atomicAdd(&counts[batch * NCLS + cls], 1.0f);
}

// ---------------- K3: class means, KL matrix, loss ----------------
__global__ __launch_bounds__(256) void final_kernel(
    const float* __restrict__ dist, const float* __restrict__ counts,
    float* __restrict__ out)
{
    __shared__ float PA[32][NBINS], LA[32][NBINS];
    __shared__ float PB[32][NBINS], LB[32][NBINS];
    __shared__ float J[32][32];
    __shared__ float pls[32];
    const int tid = threadIdx.x;

    for (int idx = tid; idx < NCLS * NBINS; idx += 256) {
        int c = idx >> 7, j = idx & 127;
        float a = dist[idx] / counts[c];
        float b = dist[NCLS * NBINS + idx] / counts[NCLS + c];
        float mm = 0.5f * (a + b);
        PA[c][j] = a;       LA[c][j] = logf(a);
        PA[c + 16][j] = mm; LA[c + 16][j] = logf(mm);
        PB[c][j] = b;       LB[c][j] = logf(b);
        PB[c + 16][j] = mm; LB[c + 16][j] = logf(mm);
    }
    __syncthreads();

    for (int pair = tid; pair < 32 * 32; pair += 256) {
        int i = pair >> 5, k = pair & 31;
        if (i == k) { J[i][k] = 0.f; continue; }
        float sA = 0.f, sB = 0.f;
        for (int jj = 0; jj < NBINS; ++jj) {
            sA += PA[i][jj] * (LA[i][jj] - LA[k][jj]);
            sB += PB[i][jj] * (LB[i][jj] - LB[k][jj]);
        }
        J[i][k] = 0.5f * (sA + sB);
    }
    __syncthreads();

    if (tid < 32) {
        float den = 0.f;
        for (int k = 0; k < 32; ++k) den += __expf(J[tid][k] * (1.0f / TAUV));
        float pos = J[tid][(tid + 16) & 31];
        pls[tid] = -(pos * (1.0f / TAUV)) + logf(den);
    }
    __syncthreads();
    if (tid == 0) {
        float s = 0.f;
        for (int i = 0; i < 32; ++i) s += pls[i];
        out[0] = s * (1.0f / 32.0f);
    }
}

extern "C" void kernel_launch(void* const* d_in, const int* in_sizes, int n_in,
                              void* d_out, int out_size, void* d_ws, size_t ws_size,
                              hipStream_t stream)
{
    const float* x1   = (const float*)d_in[0];
    const int*   y1   = (const int*)d_in[1];
    const float* x2   = (const float*)d_in[2];
    const int*   y2   = (const int*)d_in[3];
    const float* W1   = (const float*)d_in[4];
    const float* b1   = (const float*)d_in[5];
    const float* W2   = (const float*)d_in[6];
    const float* b2   = (const float*)d_in[7];
    const float* bins = (const float*)d_in[8];
    float* out = (float*)d_out;

    char* ws = (char*)d_ws;
    float* P      = (float*)ws;                                   // 8192*128 f32 = 4 MB
    char*  ws2    = ws + (size_t)8192 * 128 * sizeof(float);
    float* dist   = (float*)ws2;                                  // 2*16*128 f32
    float* counts = dist + 2 * NCLS * NBINS;                      // 2*16 f32
    __hip_bfloat16* W1T = (__hip_bfloat16*)(ws2 + 32768);         // 128x512 bf16 = 128 KB
    __hip_bfloat16* W2T = W1T + (size_t)OUT_F * IN_F;             // 128x128 bf16 = 32 KB

    hipMemsetAsync(dist, 0, (2 * NCLS * NBINS + 2 * NCLS) * sizeof(float), stream);

    prep_w<<<128, 128, 0, stream>>>(W1, W2, W1T, W2T);
    proj_mfma<<<512, 512, 0, stream>>>(x1, x2, W1T, b1, W2T, b2, P);
    pdf_kernel<<<2048, 256, 0, stream>>>(P, y1, y2, bins, dist, counts);
    final_kernel<<<1, 256, 0, stream>>>(dist, counts, out);
}

// Round 4
// 146.929 us; speedup vs baseline: 1.2029x; 1.0504x over previous
//
#include <hip/hip_runtime.h>
#include <hip/hip_bf16.h>

#define NROWS 4096
#define IN_F 512
#define OUT_F 128
#define NBINS 128
#define NCLS 16
#define EPSV 1e-8f
#define TAUV 0.1f

// -0.5 / sigma^2 * log2(e),  sigma = 0.2
#define C2EXP (-18.0336880f)

#if defined(__has_builtin)
#if __has_builtin(__builtin_amdgcn_exp2f)
#define EXP2F(x) __builtin_amdgcn_exp2f(x)
#else
#define EXP2F(x) exp2f(x)
#endif
#else
#define EXP2F(x) exp2f(x)
#endif

typedef __attribute__((ext_vector_type(8))) short bf16x8;
typedef __attribute__((ext_vector_type(4))) float f32x4;

__device__ __forceinline__ short cvt_bf16(float x) {
    __hip_bfloat16 h = __float2bfloat16(x);
    return *reinterpret_cast<short*>(&h);
}

// ---------------- K0: transpose + convert weights to bf16 ----------------
__global__ __launch_bounds__(128) void prep_w(
    const float* __restrict__ W1, const float* __restrict__ W2,
    __hip_bfloat16* __restrict__ W1T, __hip_bfloat16* __restrict__ W2T)
{
    const int n = blockIdx.x;      // 0..127 output row (= original col)
    const int t = threadIdx.x;
    for (int k = t; k < IN_F; k += 128)
        W1T[(size_t)n * IN_F + k] = __float2bfloat16(W1[(size_t)k * OUT_F + n]);
    W2T[(size_t)n * OUT_F + t] = __float2bfloat16(W2[(size_t)t * OUT_F + n]);
}

// ---------------- K1: fused MLP projection via bf16 MFMA ----------------
// 256 thr = 4 waves; 16 rows/block; wave w owns cols [32w, 32w+32) (2 tiles)
__global__ __launch_bounds__(256) void proj_mfma(
    const float* __restrict__ X1, const float* __restrict__ X2,
    const __hip_bfloat16* __restrict__ W1T, const float* __restrict__ b1,
    const __hip_bfloat16* __restrict__ W2T, const float* __restrict__ b2,
    float* __restrict__ P)
{
    __shared__ __hip_bfloat16 h_lds[16][136];   // +8 pad
    const int tid  = threadIdx.x;
    const int wave = tid >> 6;      // 0..3
    const int lane = tid & 63;
    const int lr   = lane & 15;     // M index (A) / N index (B)
    const int kg   = lane >> 4;     // k-group 0..3 (8 bf16 each)
    const int row0 = blockIdx.x * 16;
    const float* __restrict__ X = (row0 < NROWS) ? X1 : X2;
    const int xr0 = (row0 < NROWS) ? row0 : row0 - NROWS;
    const int col0 = wave * 32 + lr;
    const int col1 = col0 + 16;

    const float bb0 = b1[col0], bb1 = b1[col1];
    const float cb0 = b2[col0], cb1 = b2[col1];

    // ---- GEMM1: (16 x 512) * (512 x 32 per wave) ----
    f32x4 acc0 = {0.f, 0.f, 0.f, 0.f};
    f32x4 acc1 = {0.f, 0.f, 0.f, 0.f};
    const float* __restrict__ xrow = X + (size_t)(xr0 + lr) * IN_F;
    const __hip_bfloat16* __restrict__ w0row = W1T + (size_t)col0 * IN_F;
    const __hip_bfloat16* __restrict__ w1row = W1T + (size_t)col1 * IN_F;
    #pragma unroll 4
    for (int ks = 0; ks < IN_F / 32; ++ks) {
        const int kb = ks * 32 + kg * 8;
        float4 v0 = *reinterpret_cast<const float4*>(xrow + kb);
        float4 v1 = *reinterpret_cast<const float4*>(xrow + kb + 4);
        bf16x8 a;
        a[0] = cvt_bf16(v0.x); a[1] = cvt_bf16(v0.y);
        a[2] = cvt_bf16(v0.z); a[3] = cvt_bf16(v0.w);
        a[4] = cvt_bf16(v1.x); a[5] = cvt_bf16(v1.y);
        a[6] = cvt_bf16(v1.z); a[7] = cvt_bf16(v1.w);
        bf16x8 b0 = *reinterpret_cast<const bf16x8*>(w0row + kb);
        bf16x8 b1f = *reinterpret_cast<const bf16x8*>(w1row + kb);
        acc0 = __builtin_amdgcn_mfma_f32_16x16x32_bf16(a, b0, acc0, 0, 0, 0);
        acc1 = __builtin_amdgcn_mfma_f32_16x16x32_bf16(a, b1f, acc1, 0, 0, 0);
    }

    #pragma unroll
    for (int q = 0; q < 4; ++q) {
        h_lds[kg * 4 + q][col0] = __float2bfloat16(fmaxf(acc0[q] + bb0, 0.f));
        h_lds[kg * 4 + q][col1] = __float2bfloat16(fmaxf(acc1[q] + bb1, 0.f));
    }
    __syncthreads();

    // ---- GEMM2: (16 x 128) * (128 x 32 per wave) ----
    f32x4 c0 = {0.f, 0.f, 0.f, 0.f};
    f32x4 c1 = {0.f, 0.f, 0.f, 0.f};
    const __hip_bfloat16* __restrict__ w20 = W2T + (size_t)col0 * OUT_F;
    const __hip_bfloat16* __restrict__ w21 = W2T + (size_t)col1 * OUT_F;
    #pragma unroll
    for (int ks = 0; ks < OUT_F / 32; ++ks) {
        const int kb = ks * 32 + kg * 8;
        bf16x8 a2 = *reinterpret_cast<const bf16x8*>(&h_lds[lr][kb]);
        bf16x8 b20 = *reinterpret_cast<const bf16x8*>(w20 + kb);
        bf16x8 b21 = *reinterpret_cast<const bf16x8*>(w21 + kb);
        c0 = __builtin_amdgcn_mfma_f32_16x16x32_bf16(a2, b20, c0, 0, 0, 0);
        c1 = __builtin_amdgcn_mfma_f32_16x16x32_bf16(a2, b21, c1, 0, 0, 0);
    }
    #pragma unroll
    for (int q = 0; q < 4; ++q) {
        P[(size_t)(row0 + kg * 4 + q) * OUT_F + col0] = c0[q] + cb0;
        P[(size_t)(row0 + kg * 4 + q) * OUT_F + col1] = c1[q] + cb1;
    }
}

// ---------------- K2: 2 rows per wave, LDS-broadcast KDE ----------------
__global__ __launch_bounds__(256) void pdf_kernel(
    const float* __restrict__ P, const int* __restrict__ Y1, const int* __restrict__ Y2,
    const float* __restrict__ bins, float* __restrict__ dist, float* __restrict__ counts)
{
    __shared__ float xls[4][2][NBINS];          // [wave][row][dim]
    const int wave = threadIdx.x >> 6;
    const int lane = threadIdx.x & 63;
    const int row0 = blockIdx.x * 8 + wave * 2; // 2 rows per wave
    const int batch = row0 >> 12;               // pair never straddles 4096
    const int lrow  = row0 & 4095;

    const float bj0 = bins[lane], bj1 = bins[lane + 64];

    float p00 = P[(size_t)row0 * OUT_F + lane];
    float p01 = P[(size_t)row0 * OUT_F + 64 + lane];
    float p10 = P[(size_t)(row0 + 1) * OUT_F + lane];
    float p11 = P[(size_t)(row0 + 1) * OUT_F + 64 + lane];

    float s0 = p00 * p00 + p01 * p01;
    float s1 = p10 * p10 + p11 * p11;
    #pragma unroll
    for (int off = 32; off; off >>= 1) {
        s0 += __shfl_xor(s0, off);
        s1 += __shfl_xor(s1, off);
    }
    const float i0 = __frsqrt_rn(s0), i1 = __frsqrt_rn(s1);
    xls[wave][0][lane]      = p00 * i0;
    xls[wave][0][lane + 64] = p01 * i0;
    xls[wave][1][lane]      = p10 * i1;
    xls[wave][1][lane + 64] = p11 * i1;
    // wave-private LDS: lockstep wave64, compiler orders via lgkmcnt

    const float4* __restrict__ x0 = reinterpret_cast<const float4*>(xls[wave][0]);
    const float4* __restrict__ x1 = reinterpret_cast<const float4*>(xls[wave][1]);
    float a00 = 0.f, a01 = 0.f, a10 = 0.f, a11 = 0.f;
    #pragma unroll 4
    for (int q = 0; q < NBINS / 4; ++q) {
        float4 u = x0[q];                       // broadcast ds_read_b128
        float4 v = x1[q];
        float t;
        t = u.x - bj0; a00 += EXP2F((C2EXP * t) * t);
        t = u.x - bj1; a01 += EXP2F((C2EXP * t) * t);
        t = u.y - bj0; a00 += EXP2F((C2EXP * t) * t);
        t = u.y - bj1; a01 += EXP2F((C2EXP * t) * t);
        t = u.z - bj0; a00 += EXP2F((C2EXP * t) * t);
        t = u.z - bj1; a01 += EXP2F((C2EXP * t) * t);
        t = u.w - bj0; a00 += EXP2F((C2EXP * t) * t);
        t = u.w - bj1; a01 += EXP2F((C2EXP * t) * t);
        t = v.x - bj0; a10 += EXP2F((C2EXP * t) * t);
        t = v.x - bj1; a11 += EXP2F((C2EXP * t) * t);
        t = v.y - bj0; a10 += EXP2F((C2EXP * t) * t);
        t = v.y - bj1; a11 += EXP2F((C2EXP * t) * t);
        t = v.z - bj0; a10 += EXP2F((C2EXP * t) * t);
        t = v.z - bj1; a11 += EXP2F((C2EXP * t) * t);
        t = v.w - bj0; a10 += EXP2F((C2EXP * t) * t);
        t = v.w - bj1; a11 += EXP2F((C2EXP * t) * t);
    }

    float pdf00 = a00 * (1.0f / OUT_F), pdf01 = a01 * (1.0f / OUT_F);
    float pdf10 = a10 * (1.0f / OUT_F), pdf11 = a11 * (1.0f / OUT_F);

    float t0 = pdf00 + pdf01, t1 = pdf10 + pdf11;
    #pragma unroll
    for (int off = 32; off; off >>= 1) {
        t0 += __shfl_xor(t0, off);
        t1 += __shfl_xor(t1, off);
    }
    const float rs0 = 1.0f / (t0 + EPSV), rs1 = 1.0f / (t1 + EPSV);
    pdf00 *= rs0; pdf01 *= rs0; pdf10 *= rs1; pdf11 *= rs1;

    float m0 = fmaxf(pdf00, pdf01), m1 = fmaxf(pdf10, pdf11);
    #pragma unroll
    for (int off = 32; off; off >>= 1) {
        m0 = fmaxf(m0, __shfl_xor(m0, off));
        m1 = fmaxf(m1, __shfl_xor(m1, off));
    }
    const float e00 = __expf(pdf00 - m0), e01 = __expf(pdf01 - m0);
    const float e10 = __expf(pdf10 - m1), e11 = __expf(pdf11 - m1);
    float es0 = e00 + e01, es1 = e10 + e11;
    #pragma unroll
    for (int off = 32; off; off >>= 1) {
        es0 += __shfl_xor(es0, off);
        es1 += __shfl_xor(es1, off);
    }
    const float r0 = 1.0f / es0, r1 = 1.0f / es1;

    const int* Y = batch ? Y2 : Y1;
    const int cls0 = Y[lrow], cls1 = Y[lrow + 1];
    float* dp0 = &dist[(size_t)(batch * NCLS + cls0) * NBINS];
    float* dp1 = &dist[(size_t)(batch * NCLS + cls1) * NBINS];
    atomicAdd(dp0 + lane, e00 * r0);
    atomicAdd(dp0 + lane + 64, e01 * r0);
    atomicAdd(dp1 + lane, e10 * r1);
    atomicAdd(dp1 + lane + 64, e11 * r1);
    if (lane == 0) {
        atomicAdd(&counts[batch * NCLS + cls0], 1.0f);
        atomicAdd(&counts[batch * NCLS + cls1], 1.0f);
    }
}

// ---------------- K3: class means, KL matrix, loss ----------------
__global__ __launch_bounds__(256) void final_kernel(
    const float* __restrict__ dist, const float* __restrict__ counts,
    float* __restrict__ out)
{
    __shared__ float PA[32][NBINS], LA[32][NBINS];
    __shared__ float PB[32][NBINS], LB[32][NBINS];
    __shared__ float J[32][32];
    __shared__ float pls[32];
    const int tid = threadIdx.x;

    for (int idx = tid; idx < NCLS * NBINS; idx += 256) {
        int c = idx >> 7, j = idx & 127;
        float a = dist[idx] / counts[c];
        float b = dist[NCLS * NBINS + idx] / counts[NCLS + c];
        float mm = 0.5f * (a + b);
        PA[c][j] = a;       LA[c][j] = logf(a);
        PA[c + 16][j] = mm; LA[c + 16][j] = logf(mm);
        PB[c][j] = b;       LB[c][j] = logf(b);
        PB[c + 16][j] = mm; LB[c + 16][j] = logf(mm);
    }
    __syncthreads();

    for (int pair = tid; pair < 32 * 32; pair += 256) {
        int i = pair >> 5, k = pair & 31;
        if (i == k) { J[i][k] = 0.f; continue; }
        float sA = 0.f, sB = 0.f;
        for (int jj = 0; jj < NBINS; ++jj) {
            sA += PA[i][jj] * (LA[i][jj] - LA[k][jj]);
            sB += PB[i][jj] * (LB[i][jj] - LB[k][jj]);
        }
        J[i][k] = 0.5f * (sA + sB);
    }
    __syncthreads();

    if (tid < 32) {
        float den = 0.f;
        for (int k = 0; k < 32; ++k) den += __expf(J[tid][k] * (1.0f / TAUV));
        float pos = J[tid][(tid + 16) & 31];
        pls[tid] = -(pos * (1.0f / TAUV)) + logf(den);
    }
    __syncthreads();
    if (tid == 0) {
        float s = 0.f;
        for (int i = 0; i < 32; ++i) s += pls[i];
        out[0] = s * (1.0f / 32.0f);
    }
}

extern "C" void kernel_launch(void* const* d_in, const int* in_sizes, int n_in,
                              void* d_out, int out_size, void* d_ws, size_t ws_size,
                              hipStream_t stream)
{
    const float* x1   = (const float*)d_in[0];
    const int*   y1   = (const int*)d_in[1];
    const float* x2   = (const float*)d_in[2];
    const int*   y2   = (const int*)d_in[3];
    const float* W1   = (const float*)d_in[4];
    const float* b1   = (const float*)d_in[5];
    const float* W2   = (const float*)d_in[6];
    const float* b2   = (const float*)d_in[7];
    const float* bins = (const float*)d_in[8];
    float* out = (float*)d_out;

    char* ws = (char*)d_ws;
    float* P      = (float*)ws;                                   // 8192*128 f32 = 4 MB
    char*  ws2    = ws + (size_t)8192 * 128 * sizeof(float);
    float* dist   = (float*)ws2;                                  // 2*16*128 f32
    float* counts = dist + 2 * NCLS * NBINS;                      // 2*16 f32
    __hip_bfloat16* W1T = (__hip_bfloat16*)(ws2 + 32768);         // 128x512 bf16
    __hip_bfloat16* W2T = W1T + (size_t)OUT_F * IN_F;             // 128x128 bf16

    hipMemsetAsync(dist, 0, (2 * NCLS * NBINS + 2 * NCLS) * sizeof(float), stream);

    prep_w<<<128, 128, 0, stream>>>(W1, W2, W1T, W2T);
    proj_mfma<<<512, 256, 0, stream>>>(x1, x2, W1T, b1, W2T, b2, P);
    pdf_kernel<<<1024, 256, 0, stream>>>(P, y1, y2, bins, dist, counts);
    final_kernel<<<1, 256, 0, stream>>>(dist, counts, out);
}

// Round 5
// 127.093 us; speedup vs baseline: 1.3907x; 1.1561x over previous
//
#include <hip/hip_runtime.h>
#include <hip/hip_bf16.h>

#define NROWS 4096
#define IN_F 512
#define OUT_F 128
#define NBINS 128
#define NCLS 16
#define EPSV 1e-8f
#define TAUV 0.1f

// C2EXP = -0.5 / sigma^2 * log2(e),  sigma = 0.2
#define C2EXP (-18.0336880f)
#define M2C   (36.0673760f)   // -2 * C2EXP

#if defined(__has_builtin)
#if __has_builtin(__builtin_amdgcn_exp2f)
#define EXP2F(x) __builtin_amdgcn_exp2f(x)
#else
#define EXP2F(x) exp2f(x)
#endif
#else
#define EXP2F(x) exp2f(x)
#endif

typedef __attribute__((ext_vector_type(8))) short bf16x8;
typedef __attribute__((ext_vector_type(4))) float f32x4;
typedef __attribute__((ext_vector_type(2))) float f32x2;

__device__ __forceinline__ short cvt_bf16(float x) {
    __hip_bfloat16 h = __float2bfloat16(x);
    return *reinterpret_cast<short*>(&h);
}

// ---------------- K0: transpose + convert weights to bf16 ----------------
__global__ __launch_bounds__(128) void prep_w(
    const float* __restrict__ W1, const float* __restrict__ W2,
    __hip_bfloat16* __restrict__ W1T, __hip_bfloat16* __restrict__ W2T)
{
    const int n = blockIdx.x;      // 0..127 output row (= original col)
    const int t = threadIdx.x;
    for (int k = t; k < IN_F; k += 128)
        W1T[(size_t)n * IN_F + k] = __float2bfloat16(W1[(size_t)k * OUT_F + n]);
    W2T[(size_t)n * OUT_F + t] = __float2bfloat16(W2[(size_t)t * OUT_F + n]);
}

// ---------------- K1: MLP projection, MFMA with K-split across wave halves ----
// 1024 thr = 16 waves; wave = (half, col_tile); 16 rows/block; 512 blocks.
__global__ __launch_bounds__(1024) void proj_mfma(
    const float* __restrict__ X1, const float* __restrict__ X2,
    const __hip_bfloat16* __restrict__ W1T, const float* __restrict__ b1,
    const __hip_bfloat16* __restrict__ W2T, const float* __restrict__ b2,
    float* __restrict__ P)
{
    __shared__ float part[2][16][128];            // 16 KB partial C
    __shared__ __hip_bfloat16 h_lds[16][136];     // padded
    const int tid  = threadIdx.x;
    const int wave = tid >> 6;      // 0..15
    const int half = wave >> 3;     // K-half
    const int ct   = wave & 7;      // col tile
    const int lane = tid & 63;
    const int lr   = lane & 15;
    const int kg   = lane >> 4;
    const int row0 = blockIdx.x * 16;
    const float* __restrict__ X = (row0 < NROWS) ? X1 : X2;
    const int xr0 = (row0 < NROWS) ? row0 : row0 - NROWS;
    const int col = ct * 16 + lr;

    // ---- GEMM1: K in [half*256, half*256+256) ----
    f32x4 acc = {0.f, 0.f, 0.f, 0.f};
    const float* __restrict__ xrow = X + (size_t)(xr0 + lr) * IN_F + half * 256;
    const __hip_bfloat16* __restrict__ wrow = W1T + (size_t)col * IN_F + half * 256;
    #pragma unroll
    for (int ks = 0; ks < 8; ++ks) {
        const int kb = ks * 32 + kg * 8;
        float4 v0 = *reinterpret_cast<const float4*>(xrow + kb);
        float4 v1 = *reinterpret_cast<const float4*>(xrow + kb + 4);
        bf16x8 a;
        a[0] = cvt_bf16(v0.x); a[1] = cvt_bf16(v0.y);
        a[2] = cvt_bf16(v0.z); a[3] = cvt_bf16(v0.w);
        a[4] = cvt_bf16(v1.x); a[5] = cvt_bf16(v1.y);
        a[6] = cvt_bf16(v1.z); a[7] = cvt_bf16(v1.w);
        bf16x8 b = *reinterpret_cast<const bf16x8*>(wrow + kb);
        acc = __builtin_amdgcn_mfma_f32_16x16x32_bf16(a, b, acc, 0, 0, 0);
    }
    #pragma unroll
    for (int q = 0; q < 4; ++q) part[half][kg * 4 + q][col] = acc[q];
    __syncthreads();

    // combine halves + bias + relu -> h_lds (bf16), all 1024 threads
    #pragma unroll
    for (int idx = tid; idx < 16 * 128; idx += 1024) {
        const int m = idx >> 7, c = idx & 127;
        float v = part[0][m][c] + part[1][m][c] + b1[c];
        h_lds[m][c] = __float2bfloat16(fmaxf(v, 0.f));
    }
    __syncthreads();

    // ---- GEMM2: K=128, half does ks in {2h, 2h+1} ----
    f32x4 acc2 = {0.f, 0.f, 0.f, 0.f};
    const __hip_bfloat16* __restrict__ w2row = W2T + (size_t)col * OUT_F;
    #pragma unroll
    for (int s = 0; s < 2; ++s) {
        const int kb = (half * 2 + s) * 32 + kg * 8;
        bf16x8 a2 = *reinterpret_cast<const bf16x8*>(&h_lds[lr][kb]);
        bf16x8 b2f = *reinterpret_cast<const bf16x8*>(w2row + kb);
        acc2 = __builtin_amdgcn_mfma_f32_16x16x32_bf16(a2, b2f, acc2, 0, 0, 0);
    }
    __syncthreads();   // ensure combine-readers of `part` are done
    #pragma unroll
    for (int q = 0; q < 4; ++q) part[half][kg * 4 + q][col] = acc2[q];
    __syncthreads();

    #pragma unroll
    for (int idx = tid; idx < 16 * 128; idx += 1024) {
        const int m = idx >> 7, c = idx & 127;
        P[(size_t)(row0 + m) * OUT_F + c] = part[0][m][c] + part[1][m][c] + b2[c];
    }
}

// ---------------- K2: per-row normalize + KDE + softmax; writes P in-place ----
__global__ __launch_bounds__(256) void pdf_kernel(
    float* __restrict__ P, const float* __restrict__ bins)
{
    __shared__ float4 xls4[4][2][64];   // [wave][row][dim-pair] = (m,A,m,A)
    const int wave = threadIdx.x >> 6;
    const int lane = threadIdx.x & 63;
    const int row0 = blockIdx.x * 8 + wave * 2;

    const float bj0 = bins[lane], bj1 = bins[lane + 64];
    const float B0 = C2EXP * bj0 * bj0, B1 = C2EXP * bj1 * bj1;

    float p00 = P[(size_t)row0 * OUT_F + lane];
    float p01 = P[(size_t)row0 * OUT_F + 64 + lane];
    float p10 = P[(size_t)(row0 + 1) * OUT_F + lane];
    float p11 = P[(size_t)(row0 + 1) * OUT_F + 64 + lane];

    float s0 = p00 * p00 + p01 * p01;
    float s1 = p10 * p10 + p11 * p11;
    #pragma unroll
    for (int off = 32; off; off >>= 1) {
        s0 += __shfl_xor(s0, off);
        s1 += __shfl_xor(s1, off);
    }
    const float i0 = __frsqrt_rn(s0), i1 = __frsqrt_rn(s1);
    const float x00 = p00 * i0, x01 = p01 * i0;
    const float x10 = p10 * i1, x11 = p11 * i1;

    // stage (m_d, A_d) per dim:  arg = m_d*b_j + A_d + B_j = C2EXP*(x_d-b_j)^2
    {
        f32x2* w0 = reinterpret_cast<f32x2*>(&xls4[wave][0][0]);
        f32x2* w1 = reinterpret_cast<f32x2*>(&xls4[wave][1][0]);
        w0[lane]      = (f32x2){x00 * M2C, C2EXP * x00 * x00};
        w0[lane + 64] = (f32x2){x01 * M2C, C2EXP * x01 * x01};
        w1[lane]      = (f32x2){x10 * M2C, C2EXP * x10 * x10};
        w1[lane + 64] = (f32x2){x11 * M2C, C2EXP * x11 * x11};
    }
    // wave-private LDS: lockstep wave64, compiler orders via lgkmcnt

    const float4* __restrict__ x0 = &xls4[wave][0][0];
    const float4* __restrict__ x1 = &xls4[wave][1][0];
    const f32x2 BJ = {bj0, bj1};
    const f32x2 BB = {B0, B1};
    f32x2 a0 = {0.f, 0.f}, a1 = {0.f, 0.f};
    #pragma unroll 4
    for (int q = 0; q < 64; ++q) {
        float4 u = x0[q];                       // (m,A, m,A) broadcast b128
        float4 v = x1[q];
        f32x2 g;
        g = BJ * u.x + (BB + u.y);
        a0 += (f32x2){EXP2F(g.x), EXP2F(g.y)};
        g = BJ * u.z + (BB + u.w);
        a0 += (f32x2){EXP2F(g.x), EXP2F(g.y)};
        g = BJ * v.x + (BB + v.y);
        a1 += (f32x2){EXP2F(g.x), EXP2F(g.y)};
        g = BJ * v.z + (BB + v.w);
        a1 += (f32x2){EXP2F(g.x), EXP2F(g.y)};
    }

    float pdf00 = a0.x * (1.0f / OUT_F), pdf01 = a0.y * (1.0f / OUT_F);
    float pdf10 = a1.x * (1.0f / OUT_F), pdf11 = a1.y * (1.0f / OUT_F);

    float t0 = pdf00 + pdf01, t1 = pdf10 + pdf11;
    #pragma unroll
    for (int off = 32; off; off >>= 1) {
        t0 += __shfl_xor(t0, off);
        t1 += __shfl_xor(t1, off);
    }
    const float rs0 = 1.0f / (t0 + EPSV), rs1 = 1.0f / (t1 + EPSV);
    pdf00 *= rs0; pdf01 *= rs0; pdf10 *= rs1; pdf11 *= rs1;

    float m0 = fmaxf(pdf00, pdf01), m1 = fmaxf(pdf10, pdf11);
    #pragma unroll
    for (int off = 32; off; off >>= 1) {
        m0 = fmaxf(m0, __shfl_xor(m0, off));
        m1 = fmaxf(m1, __shfl_xor(m1, off));
    }
    const float e00 = __expf(pdf00 - m0), e01 = __expf(pdf01 - m0);
    const float e10 = __expf(pdf10 - m1), e11 = __expf(pdf11 - m1);
    float es0 = e00 + e01, es1 = e10 + e11;
    #pragma unroll
    for (int off = 32; off; off >>= 1) {
        es0 += __shfl_xor(es0, off);
        es1 += __shfl_xor(es1, off);
    }
    const float r0 = 1.0f / es0, r1 = 1.0f / es1;

    // in-place: this wave is the only reader of these rows
    P[(size_t)row0 * OUT_F + lane]            = e00 * r0;
    P[(size_t)row0 * OUT_F + 64 + lane]       = e01 * r0;
    P[(size_t)(row0 + 1) * OUT_F + lane]      = e10 * r1;
    P[(size_t)(row0 + 1) * OUT_F + 64 + lane] = e11 * r1;
}

// ---------------- K3: deterministic segment reduction (no atomics) ----------
// 128 blocks = (batch, class, quarter); each scans 1024 rows predicated.
__global__ __launch_bounds__(256) void reduce_kernel(
    const float* __restrict__ SM, const int* __restrict__ Y1, const int* __restrict__ Y2,
    float* __restrict__ pdist, float* __restrict__ pcnt)
{
    __shared__ int lab_s[1024];
    __shared__ float sd[2][128];
    __shared__ float cc[2];
    const int b = blockIdx.x;               // 0..127
    const int batch = b >> 6, cls = (b >> 2) & 15, qt = b & 3;
    const int tid = threadIdx.x;
    const int j = tid & 127, half = tid >> 7;
    const int* __restrict__ Y = batch ? Y2 : Y1;

    for (int i = tid; i < 1024; i += 256) lab_s[i] = Y[qt * 1024 + i];
    __syncthreads();

    const float* __restrict__ base =
        SM + ((size_t)batch * 4096 + (size_t)qt * 1024) * OUT_F + j;
    float acc = 0.f;
    int cnt = 0;
    #pragma unroll 4
    for (int r = half; r < 1024; r += 2) {
        const bool hit = (lab_s[r] == cls);
        const float v = base[(size_t)r * OUT_F];
        acc += hit ? v : 0.f;
        cnt += hit ? 1 : 0;
    }
    sd[half][j] = acc;
    if (j == 0) cc[half] = (float)cnt;
    __syncthreads();
    if (tid < 128) pdist[(size_t)b * 128 + tid] = sd[0][tid] + sd[1][tid];
    if (tid == 0) pcnt[b] = cc[0] + cc[1];
}

// ---------------- K4: merge partials, class means, KL matrix, loss ----------
__global__ __launch_bounds__(256) void final_kernel(
    const float* __restrict__ pdist, const float* __restrict__ pcnt,
    float* __restrict__ out)
{
    __shared__ float PA[32][NBINS], LA[32][NBINS];
    __shared__ float PB[32][NBINS], LB[32][NBINS];
    __shared__ float J[32][32];
    __shared__ float pls[32];
    __shared__ float cnt[32];
    const int tid = threadIdx.x;

    if (tid < 32) {
        const int batch = tid >> 4, c = tid & 15;
        float s = 0.f;
        #pragma unroll
        for (int q = 0; q < 4; ++q) s += pcnt[batch * 64 + c * 4 + q];
        cnt[tid] = s;
    }
    __syncthreads();

    for (int idx = tid; idx < NCLS * NBINS; idx += 256) {
        const int c = idx >> 7, j = idx & 127;
        float a = 0.f, bsum = 0.f;
        #pragma unroll
        for (int q = 0; q < 4; ++q) {
            a    += pdist[(size_t)(c * 4 + q) * 128 + j];
            bsum += pdist[(size_t)(64 + c * 4 + q) * 128 + j];
        }
        a /= cnt[c];
        bsum /= cnt[16 + c];
        const float mm = 0.5f * (a + bsum);
        PA[c][j] = a;          LA[c][j] = logf(a);
        PA[c + 16][j] = mm;    LA[c + 16][j] = logf(mm);
        PB[c][j] = bsum;       LB[c][j] = logf(bsum);
        PB[c + 16][j] = mm;    LB[c + 16][j] = logf(mm);
    }
    __syncthreads();

    for (int pair = tid; pair < 32 * 32; pair += 256) {
        const int i = pair >> 5, k = pair & 31;
        if (i == k) { J[i][k] = 0.f; continue; }
        float sA = 0.f, sB = 0.f;
        for (int jj = 0; jj < NBINS; ++jj) {
            sA += PA[i][jj] * (LA[i][jj] - LA[k][jj]);
            sB += PB[i][jj] * (LB[i][jj] - LB[k][jj]);
        }
        J[i][k] = 0.5f * (sA + sB);
    }
    __syncthreads();

    if (tid < 32) {
        float den = 0.f;
        for (int k = 0; k < 32; ++k) den += __expf(J[tid][k] * (1.0f / TAUV));
        const float pos = J[tid][(tid + 16) & 31];
        pls[tid] = -(pos * (1.0f / TAUV)) + logf(den);
    }
    __syncthreads();
    if (tid == 0) {
        float s = 0.f;
        for (int i = 0; i < 32; ++i) s += pls[i];
        out[0] = s * (1.0f / 32.0f);
    }
}

extern "C" void kernel_launch(void* const* d_in, const int* in_sizes, int n_in,
                              void* d_out, int out_size, void* d_ws, size_t ws_size,
                              hipStream_t stream)
{
    const float* x1   = (const float*)d_in[0];
    const int*   y1   = (const int*)d_in[1];
    const float* x2   = (const float*)d_in[2];
    const int*   y2   = (const int*)d_in[3];
    const float* W1   = (const float*)d_in[4];
    const float* b1   = (const float*)d_in[5];
    const float* W2   = (const float*)d_in[6];
    const float* b2   = (const float*)d_in[7];
    const float* bins = (const float*)d_in[8];
    float* out = (float*)d_out;

    char* ws = (char*)d_ws;
    float* P     = (float*)ws;                                    // 8192*128 f32 = 4 MB
    char*  ws2   = ws + (size_t)8192 * 128 * sizeof(float);
    float* pdist = (float*)ws2;                                   // 128*128 f32 = 64 KB
    float* pcnt  = pdist + 128 * 128;                             // 128 f32
    __hip_bfloat16* W1T = (__hip_bfloat16*)(ws2 + 128 * 128 * 4 + 1024); // 128x512 bf16
    __hip_bfloat16* W2T = W1T + (size_t)OUT_F * IN_F;             // 128x128 bf16

    prep_w<<<128, 128, 0, stream>>>(W1, W2, W1T, W2T);
    proj_mfma<<<512, 1024, 0, stream>>>(x1, x2, W1T, b1, W2T, b2, P);
    pdf_kernel<<<1024, 256, 0, stream>>>(P, bins);
    reduce_kernel<<<128, 256, 0, stream>>>(P, y1, y2, pdist, pcnt);
    final_kernel<<<1, 256, 0, stream>>>(pdist, pcnt, out);
}

// Round 6
// 93.336 us; speedup vs baseline: 1.8936x; 1.3617x over previous
//
#include <hip/hip_runtime.h>
#include <hip/hip_bf16.h>

#define NROWS 4096
#define IN_F 512
#define OUT_F 128
#define NBINS 128
#define NCLS 16
#define EPSV 1e-8f
#define TAUV 0.1f

// C2EXP = -0.5 / sigma^2 * log2(e),  sigma = 0.2
#define C2EXP (-18.0336880f)
#define M2C   (36.0673760f)   // -2 * C2EXP

#if defined(__has_builtin)
#if __has_builtin(__builtin_amdgcn_exp2f)
#define EXP2F(x) __builtin_amdgcn_exp2f(x)
#else
#define EXP2F(x) exp2f(x)
#endif
#else
#define EXP2F(x) exp2f(x)
#endif

typedef __attribute__((ext_vector_type(8))) short bf16x8;
typedef __attribute__((ext_vector_type(4))) float f32x4;
typedef __attribute__((ext_vector_type(2))) float f32x2;

__device__ __forceinline__ short cvt_bf16(float x) {
    __hip_bfloat16 h = __float2bfloat16(x);
    return *reinterpret_cast<short*>(&h);
}

// ---------------- K0: transpose + convert weights to bf16 ----------------
__global__ __launch_bounds__(128) void prep_w(
    const float* __restrict__ W1, const float* __restrict__ W2,
    __hip_bfloat16* __restrict__ W1T, __hip_bfloat16* __restrict__ W2T)
{
    const int n = blockIdx.x;      // 0..127 output row (= original col)
    const int t = threadIdx.x;
    for (int k = t; k < IN_F; k += 128)
        W1T[(size_t)n * IN_F + k] = __float2bfloat16(W1[(size_t)k * OUT_F + n]);
    W2T[(size_t)n * OUT_F + t] = __float2bfloat16(W2[(size_t)t * OUT_F + n]);
}

// ---------------- K1: fused MLP projection (MFMA) + normalize + KDE + softmax
// 256 thr = 4 waves; 16 rows/block; 512 blocks.
// GEMM phase: wave w owns cols [32w, 32w+32) (2 MFMA col-tiles).
// PDF phase:  wave w owns rows [4w, 4w+4); lane owns bins {l, l+64}.
__global__ __launch_bounds__(256) void fused_proj_pdf(
    const float* __restrict__ X1, const float* __restrict__ X2,
    const __hip_bfloat16* __restrict__ W1T, const float* __restrict__ b1,
    const __hip_bfloat16* __restrict__ W2T, const float* __restrict__ b2,
    const float* __restrict__ bins, float* __restrict__ SM)
{
    __shared__ __hip_bfloat16 h_lds[16][136];   // 4.4 KB
    __shared__ float pout[16][128];             // 8 KB projected rows
    __shared__ f32x2 rowMA[4][128];             // 4 KB per-wave (m,A) dim table
    const int tid  = threadIdx.x;
    const int wave = tid >> 6;      // 0..3
    const int lane = tid & 63;
    const int lr   = lane & 15;
    const int kg   = lane >> 4;
    const int row0 = blockIdx.x * 16;
    const float* __restrict__ X = (row0 < NROWS) ? X1 : X2;
    const int xr0 = (row0 < NROWS) ? row0 : row0 - NROWS;
    const int col0 = wave * 32 + lr;
    const int col1 = col0 + 16;

    const float bb0 = b1[col0], bb1 = b1[col1];
    const float cb0 = b2[col0], cb1 = b2[col1];

    // ---- GEMM1: (16 x 512) * (512 x 32 per wave) ----
    f32x4 acc0 = {0.f, 0.f, 0.f, 0.f};
    f32x4 acc1 = {0.f, 0.f, 0.f, 0.f};
    {
        const float* __restrict__ xrow = X + (size_t)(xr0 + lr) * IN_F;
        const __hip_bfloat16* __restrict__ w0row = W1T + (size_t)col0 * IN_F;
        const __hip_bfloat16* __restrict__ w1row = W1T + (size_t)col1 * IN_F;
        #pragma unroll 4
        for (int ks = 0; ks < IN_F / 32; ++ks) {
            const int kb = ks * 32 + kg * 8;
            float4 v0 = *reinterpret_cast<const float4*>(xrow + kb);
            float4 v1 = *reinterpret_cast<const float4*>(xrow + kb + 4);
            bf16x8 a;
            a[0] = cvt_bf16(v0.x); a[1] = cvt_bf16(v0.y);
            a[2] = cvt_bf16(v0.z); a[3] = cvt_bf16(v0.w);
            a[4] = cvt_bf16(v1.x); a[5] = cvt_bf16(v1.y);
            a[6] = cvt_bf16(v1.z); a[7] = cvt_bf16(v1.w);
            bf16x8 b0 = *reinterpret_cast<const bf16x8*>(w0row + kb);
            bf16x8 b1f = *reinterpret_cast<const bf16x8*>(w1row + kb);
            acc0 = __builtin_amdgcn_mfma_f32_16x16x32_bf16(a, b0, acc0, 0, 0, 0);
            acc1 = __builtin_amdgcn_mfma_f32_16x16x32_bf16(a, b1f, acc1, 0, 0, 0);
        }
    }
    #pragma unroll
    for (int q = 0; q < 4; ++q) {
        h_lds[kg * 4 + q][col0] = __float2bfloat16(fmaxf(acc0[q] + bb0, 0.f));
        h_lds[kg * 4 + q][col1] = __float2bfloat16(fmaxf(acc1[q] + bb1, 0.f));
    }
    __syncthreads();

    // ---- GEMM2: (16 x 128) * (128 x 32 per wave) ----
    f32x4 c0 = {0.f, 0.f, 0.f, 0.f};
    f32x4 c1 = {0.f, 0.f, 0.f, 0.f};
    {
        const __hip_bfloat16* __restrict__ w20 = W2T + (size_t)col0 * OUT_F;
        const __hip_bfloat16* __restrict__ w21 = W2T + (size_t)col1 * OUT_F;
        #pragma unroll
        for (int ks = 0; ks < OUT_F / 32; ++ks) {
            const int kb = ks * 32 + kg * 8;
            bf16x8 a2 = *reinterpret_cast<const bf16x8*>(&h_lds[lr][kb]);
            bf16x8 b20 = *reinterpret_cast<const bf16x8*>(w20 + kb);
            bf16x8 b21 = *reinterpret_cast<const bf16x8*>(w21 + kb);
            c0 = __builtin_amdgcn_mfma_f32_16x16x32_bf16(a2, b20, c0, 0, 0, 0);
            c1 = __builtin_amdgcn_mfma_f32_16x16x32_bf16(a2, b21, c1, 0, 0, 0);
        }
    }
    #pragma unroll
    for (int q = 0; q < 4; ++q) {
        pout[kg * 4 + q][col0] = c0[q] + cb0;
        pout[kg * 4 + q][col1] = c1[q] + cb1;
    }
    __syncthreads();

    // ---- PDF phase: wave w handles rows [4w, 4w+4) ----
    const float bj0 = bins[lane], bj1 = bins[lane + 64];
    const float B0 = C2EXP * bj0 * bj0, B1 = C2EXP * bj1 * bj1;
    const f32x2 BJ = {bj0, bj1};
    const f32x2 BB = {B0, B1};

    #pragma unroll
    for (int mr = 0; mr < 4; ++mr) {
        const int m = wave * 4 + mr;
        const float v0 = pout[m][lane], v1 = pout[m][lane + 64];
        float ss = v0 * v0 + v1 * v1;
        #pragma unroll
        for (int off = 32; off; off >>= 1) ss += __shfl_xor(ss, off);
        const float inv = __frsqrt_rn(ss);
        const float x0 = v0 * inv, x1 = v1 * inv;

        rowMA[wave][lane]      = (f32x2){x0 * M2C, C2EXP * x0 * x0};
        rowMA[wave][lane + 64] = (f32x2){x1 * M2C, C2EXP * x1 * x1};
        // wave-private LDS, lockstep wave64: compiler orders via lgkmcnt

        const float4* __restrict__ tb = reinterpret_cast<const float4*>(&rowMA[wave][0]);
        f32x2 a = {0.f, 0.f};
        #pragma unroll 8
        for (int q = 0; q < 64; ++q) {
            float4 u = tb[q];                   // 2 dims: (m,A, m,A)
            f32x2 g;
            g = BJ * u.x + (BB + u.y);
            a += (f32x2){EXP2F(g.x), EXP2F(g.y)};
            g = BJ * u.z + (BB + u.w);
            a += (f32x2){EXP2F(g.x), EXP2F(g.y)};
        }

        float pdf0 = a.x * (1.0f / OUT_F), pdf1 = a.y * (1.0f / OUT_F);
        float t = pdf0 + pdf1;
        #pragma unroll
        for (int off = 32; off; off >>= 1) t += __shfl_xor(t, off);
        const float rs = 1.0f / (t + EPSV);
        pdf0 *= rs; pdf1 *= rs;

        float mx = fmaxf(pdf0, pdf1);
        #pragma unroll
        for (int off = 32; off; off >>= 1) mx = fmaxf(mx, __shfl_xor(mx, off));
        const float e0 = __expf(pdf0 - mx), e1 = __expf(pdf1 - mx);
        float es = e0 + e1;
        #pragma unroll
        for (int off = 32; off; off >>= 1) es += __shfl_xor(es, off);
        const float r = 1.0f / es;

        SM[(size_t)(row0 + m) * OUT_F + lane]      = e0 * r;
        SM[(size_t)(row0 + m) * OUT_F + 64 + lane] = e1 * r;
    }
}

// ---------------- K2: deterministic segment reduction (no atomics) ----------
// 256 blocks = (batch, class, eighth); each scans 512 rows predicated.
__global__ __launch_bounds__(256) void reduce_kernel(
    const float* __restrict__ SM, const int* __restrict__ Y1, const int* __restrict__ Y2,
    float* __restrict__ pdist, float* __restrict__ pcnt)
{
    __shared__ int lab_s[512];
    __shared__ float sd[2][128];
    __shared__ float cc[2];
    const int b = blockIdx.x;               // 0..255
    const int batch = b >> 7, cls = (b >> 3) & 15, eig = b & 7;
    const int tid = threadIdx.x;
    const int j = tid & 127, half = tid >> 7;
    const int* __restrict__ Y = batch ? Y2 : Y1;

    for (int i = tid; i < 512; i += 256) lab_s[i] = Y[eig * 512 + i];
    __syncthreads();

    const float* __restrict__ base =
        SM + ((size_t)batch * 4096 + (size_t)eig * 512) * OUT_F + j;
    float acc = 0.f;
    int cnt = 0;
    #pragma unroll 8
    for (int r = half; r < 512; r += 2) {
        const bool hit = (lab_s[r] == cls);
        const float v = base[(size_t)r * OUT_F];
        acc += hit ? v : 0.f;
        cnt += hit ? 1 : 0;
    }
    sd[half][j] = acc;
    if (j == 0) cc[half] = (float)cnt;
    __syncthreads();
    if (tid < 128) pdist[(size_t)b * 128 + tid] = sd[0][tid] + sd[1][tid];
    if (tid == 0) pcnt[b] = cc[0] + cc[1];
}

// ---------------- K3: merge partials, class means, KL matrix, loss ----------
__global__ __launch_bounds__(256) void final_kernel(
    const float* __restrict__ pdist, const float* __restrict__ pcnt,
    float* __restrict__ out)
{
    __shared__ float PA[32][NBINS], LA[32][NBINS];
    __shared__ float PB[32][NBINS], LB[32][NBINS];
    __shared__ float J[32][32];
    __shared__ float pls[32];
    __shared__ float cnt[32];
    const int tid = threadIdx.x;

    if (tid < 32) {
        const int batch = tid >> 4, c = tid & 15;
        float s = 0.f;
        #pragma unroll
        for (int q = 0; q < 8; ++q) s += pcnt[batch * 128 + c * 8 + q];
        cnt[tid] = s;
    }
    __syncthreads();

    for (int idx = tid; idx < NCLS * NBINS; idx += 256) {
        const int c = idx >> 7, j = idx & 127;
        float a = 0.f, bsum = 0.f;
        #pragma unroll
        for (int q = 0; q < 8; ++q) {
            a    += pdist[(size_t)(c * 8 + q) * 128 + j];
            bsum += pdist[(size_t)(128 + c * 8 + q) * 128 + j];
        }
        a /= cnt[c];
        bsum /= cnt[16 + c];
        const float mm = 0.5f * (a + bsum);
        PA[c][j] = a;          LA[c][j] = logf(a);
        PA[c + 16][j] = mm;    LA[c + 16][j] = logf(mm);
        PB[c][j] = bsum;       LB[c][j] = logf(bsum);
        PB[c + 16][j] = mm;    LB[c + 16][j] = logf(mm);
    }
    __syncthreads();

    for (int pair = tid; pair < 32 * 32; pair += 256) {
        const int i = pair >> 5, k = pair & 31;
        if (i == k) { J[i][k] = 0.f; continue; }
        float sA = 0.f, sB = 0.f;
        for (int jj = 0; jj < NBINS; ++jj) {
            sA += PA[i][jj] * (LA[i][jj] - LA[k][jj]);
            sB += PB[i][jj] * (LB[i][jj] - LB[k][jj]);
        }
        J[i][k] = 0.5f * (sA + sB);
    }
    __syncthreads();

    if (tid < 32) {
        float den = 0.f;
        for (int k = 0; k < 32; ++k) den += __expf(J[tid][k] * (1.0f / TAUV));
        const float pos = J[tid][(tid + 16) & 31];
        pls[tid] = -(pos * (1.0f / TAUV)) + logf(den);
    }
    __syncthreads();
    if (tid == 0) {
        float s = 0.f;
        for (int i = 0; i < 32; ++i) s += pls[i];
        out[0] = s * (1.0f / 32.0f);
    }
}

extern "C" void kernel_launch(void* const* d_in, const int* in_sizes, int n_in,
                              void* d_out, int out_size, void* d_ws, size_t ws_size,
                              hipStream_t stream)
{
    const float* x1   = (const float*)d_in[0];
    const int*   y1   = (const int*)d_in[1];
    const float* x2   = (const float*)d_in[2];
    const int*   y2   = (const int*)d_in[3];
    const float* W1   = (const float*)d_in[4];
    const float* b1   = (const float*)d_in[5];
    const float* W2   = (const float*)d_in[6];
    const float* b2   = (const float*)d_in[7];
    const float* bins = (const float*)d_in[8];
    float* out = (float*)d_out;

    char* ws = (char*)d_ws;
    float* SM    = (float*)ws;                                    // 8192*128 f32 = 4 MB
    char*  ws2   = ws + (size_t)8192 * 128 * sizeof(float);
    float* pdist = (float*)ws2;                                   // 256*128 f32 = 128 KB
    float* pcnt  = pdist + 256 * 128;                             // 256 f32
    __hip_bfloat16* W1T = (__hip_bfloat16*)(ws2 + 256 * 128 * 4 + 1024); // 128x512 bf16
    __hip_bfloat16* W2T = W1T + (size_t)OUT_F * IN_F;             // 128x128 bf16

    prep_w<<<128, 128, 0, stream>>>(W1, W2, W1T, W2T);
    fused_proj_pdf<<<512, 256, 0, stream>>>(x1, x2, W1T, b1, W2T, b2, bins, SM);
    reduce_kernel<<<256, 256, 0, stream>>>(SM, y1, y2, pdist, pcnt);
    final_kernel<<<1, 256, 0, stream>>>(pdist, pcnt, out);
}

// Round 7
// 85.180 us; speedup vs baseline: 2.0750x; 1.0958x over previous
//
#include <hip/hip_runtime.h>
#include <hip/hip_bf16.h>

#define NROWS 4096
#define IN_F 512
#define OUT_F 128
#define NBINS 128
#define NCLS 16
#define EPSV 1e-8f
#define TAUV 0.1f

// C2EXP = -0.5 / sigma^2 * log2(e),  sigma = 0.2
#define C2EXP (-18.0336880f)
#define M2C   (36.0673760f)   // -2 * C2EXP

#if defined(__has_builtin)
#if __has_builtin(__builtin_amdgcn_exp2f)
#define EXP2F(x) __builtin_amdgcn_exp2f(x)
#else
#define EXP2F(x) exp2f(x)
#endif
#else
#define EXP2F(x) exp2f(x)
#endif

typedef __attribute__((ext_vector_type(8))) short bf16x8;
typedef __attribute__((ext_vector_type(4))) float f32x4;
typedef __attribute__((ext_vector_type(2))) float f32x2;

__device__ __forceinline__ short cvt_bf16(float x) {
    __hip_bfloat16 h = __float2bfloat16(x);
    return *reinterpret_cast<short*>(&h);
}

// ---------------- K0: transpose + convert weights to bf16 ----------------
__global__ __launch_bounds__(128) void prep_w(
    const float* __restrict__ W1, const float* __restrict__ W2,
    __hip_bfloat16* __restrict__ W1T, __hip_bfloat16* __restrict__ W2T)
{
    const int n = blockIdx.x;      // 0..127 output row (= original col)
    const int t = threadIdx.x;
    for (int k = t; k < IN_F; k += 128)
        W1T[(size_t)n * IN_F + k] = __float2bfloat16(W1[(size_t)k * OUT_F + n]);
    W2T[(size_t)n * OUT_F + t] = __float2bfloat16(W2[(size_t)t * OUT_F + n]);
}

// ---------------- K1: fused MLP projection (MFMA) + normalize + KDE + softmax
// 512 thr = 8 waves; 16 rows/block; 512 blocks.
// Stage X tile once in LDS (bf16). GEMM: wave w owns cols [16w, 16w+16).
// PDF phase: wave w owns rows {2w, 2w+1}; lane owns bins {l, l+64}.
__global__ __launch_bounds__(512) void fused_proj_pdf(
    const float* __restrict__ X1, const float* __restrict__ X2,
    const __hip_bfloat16* __restrict__ W1T, const float* __restrict__ b1,
    const __hip_bfloat16* __restrict__ W2T, const float* __restrict__ b2,
    const float* __restrict__ bins, float* __restrict__ SM)
{
    __shared__ __hip_bfloat16 xb[16][IN_F + 8];   // 16.6 KB, +8 bf16 pad
    __shared__ __hip_bfloat16 h_lds[16][136];     // 4.3 KB
    __shared__ float pout[16][128];               // 8 KB
    __shared__ f32x2 rowMA[8][2][128];            // 16 KB (m,A) tables
    const int tid  = threadIdx.x;
    const int wave = tid >> 6;      // 0..7 (col tile / row pair)
    const int lane = tid & 63;
    const int lr   = lane & 15;
    const int kg   = lane >> 4;
    const int row0 = blockIdx.x * 16;
    const float* __restrict__ X = (row0 < NROWS) ? X1 : X2;
    const int xr0 = (row0 < NROWS) ? row0 : row0 - NROWS;
    const int col = wave * 16 + lr;

    // ---- Phase 0: stage X tile (16 x 512 f32 -> bf16 LDS), coalesced ----
    for (int i = tid; i < 16 * 128; i += 512) {
        const int r = i >> 7, c4 = i & 127;
        float4 v = *reinterpret_cast<const float4*>(
            X + (size_t)(xr0 + r) * IN_F + c4 * 4);
        short4 s;
        s.x = cvt_bf16(v.x); s.y = cvt_bf16(v.y);
        s.z = cvt_bf16(v.z); s.w = cvt_bf16(v.w);
        *reinterpret_cast<short4*>(&xb[r][c4 * 4]) = s;
    }
    __syncthreads();

    // ---- GEMM1: (16 x 512) * (512 x 16 per wave) ----
    f32x4 acc = {0.f, 0.f, 0.f, 0.f};
    {
        const __hip_bfloat16* __restrict__ wrow = W1T + (size_t)col * IN_F;
        #pragma unroll 4
        for (int ks = 0; ks < IN_F / 32; ++ks) {
            const int kb = ks * 32 + kg * 8;
            bf16x8 a = *reinterpret_cast<const bf16x8*>(&xb[lr][kb]);
            bf16x8 b = *reinterpret_cast<const bf16x8*>(wrow + kb);
            acc = __builtin_amdgcn_mfma_f32_16x16x32_bf16(a, b, acc, 0, 0, 0);
        }
    }
    {
        const float bb = b1[col];
        #pragma unroll
        for (int q = 0; q < 4; ++q)
            h_lds[kg * 4 + q][col] = __float2bfloat16(fmaxf(acc[q] + bb, 0.f));
    }
    __syncthreads();

    // ---- GEMM2: (16 x 128) * (128 x 16 per wave) ----
    f32x4 c2 = {0.f, 0.f, 0.f, 0.f};
    {
        const __hip_bfloat16* __restrict__ w2row = W2T + (size_t)col * OUT_F;
        #pragma unroll
        for (int ks = 0; ks < OUT_F / 32; ++ks) {
            const int kb = ks * 32 + kg * 8;
            bf16x8 a2 = *reinterpret_cast<const bf16x8*>(&h_lds[lr][kb]);
            bf16x8 b2f = *reinterpret_cast<const bf16x8*>(w2row + kb);
            c2 = __builtin_amdgcn_mfma_f32_16x16x32_bf16(a2, b2f, c2, 0, 0, 0);
        }
    }
    {
        const float cb = b2[col];
        #pragma unroll
        for (int q = 0; q < 4; ++q)
            pout[kg * 4 + q][col] = c2[q] + cb;
    }
    __syncthreads();

    // ---- PDF phase: wave handles rows {2*wave, 2*wave+1}, dual ILP chains ----
    const int m0 = wave * 2, m1 = m0 + 1;
    const float bj0 = bins[lane], bj1 = bins[lane + 64];
    const float B0 = C2EXP * bj0 * bj0, B1 = C2EXP * bj1 * bj1;
    const f32x2 BJ = {bj0, bj1};
    const f32x2 BB = {B0, B1};

    const float p00 = pout[m0][lane], p01 = pout[m0][lane + 64];
    const float p10 = pout[m1][lane], p11 = pout[m1][lane + 64];

    float s0 = p00 * p00 + p01 * p01;
    float s1 = p10 * p10 + p11 * p11;
    #pragma unroll
    for (int off = 32; off; off >>= 1) {
        s0 += __shfl_xor(s0, off);
        s1 += __shfl_xor(s1, off);
    }
    const float i0 = __frsqrt_rn(s0), i1 = __frsqrt_rn(s1);
    const float x00 = p00 * i0, x01 = p01 * i0;
    const float x10 = p10 * i1, x11 = p11 * i1;

    rowMA[wave][0][lane]      = (f32x2){x00 * M2C, C2EXP * x00 * x00};
    rowMA[wave][0][lane + 64] = (f32x2){x01 * M2C, C2EXP * x01 * x01};
    rowMA[wave][1][lane]      = (f32x2){x10 * M2C, C2EXP * x10 * x10};
    rowMA[wave][1][lane + 64] = (f32x2){x11 * M2C, C2EXP * x11 * x11};
    // wave-private LDS, lockstep wave64: compiler orders via lgkmcnt

    const float4* __restrict__ t0b = reinterpret_cast<const float4*>(&rowMA[wave][0][0]);
    const float4* __restrict__ t1b = reinterpret_cast<const float4*>(&rowMA[wave][1][0]);
    f32x2 a0 = {0.f, 0.f}, a1 = {0.f, 0.f};
    #pragma unroll 4
    for (int q = 0; q < 64; ++q) {
        float4 u = t0b[q];                  // (m,A, m,A) row0, broadcast b128
        float4 v = t1b[q];                  // row1
        f32x2 g;
        g = BJ * u.x + (BB + u.y);
        a0 += (f32x2){EXP2F(g.x), EXP2F(g.y)};
        g = BJ * u.z + (BB + u.w);
        a0 += (f32x2){EXP2F(g.x), EXP2F(g.y)};
        g = BJ * v.x + (BB + v.y);
        a1 += (f32x2){EXP2F(g.x), EXP2F(g.y)};
        g = BJ * v.z + (BB + v.w);
        a1 += (f32x2){EXP2F(g.x), EXP2F(g.y)};
    }

    float pdf00 = a0.x * (1.0f / OUT_F), pdf01 = a0.y * (1.0f / OUT_F);
    float pdf10 = a1.x * (1.0f / OUT_F), pdf11 = a1.y * (1.0f / OUT_F);

    float t0 = pdf00 + pdf01, t1 = pdf10 + pdf11;
    #pragma unroll
    for (int off = 32; off; off >>= 1) {
        t0 += __shfl_xor(t0, off);
        t1 += __shfl_xor(t1, off);
    }
    const float rs0 = 1.0f / (t0 + EPSV), rs1 = 1.0f / (t1 + EPSV);
    pdf00 *= rs0; pdf01 *= rs0; pdf10 *= rs1; pdf11 *= rs1;

    float mx0 = fmaxf(pdf00, pdf01), mx1 = fmaxf(pdf10, pdf11);
    #pragma unroll
    for (int off = 32; off; off >>= 1) {
        mx0 = fmaxf(mx0, __shfl_xor(mx0, off));
        mx1 = fmaxf(mx1, __shfl_xor(mx1, off));
    }
    const float e00 = __expf(pdf00 - mx0), e01 = __expf(pdf01 - mx0);
    const float e10 = __expf(pdf10 - mx1), e11 = __expf(pdf11 - mx1);
    float es0 = e00 + e01, es1 = e10 + e11;
    #pragma unroll
    for (int off = 32; off; off >>= 1) {
        es0 += __shfl_xor(es0, off);
        es1 += __shfl_xor(es1, off);
    }
    const float r0 = 1.0f / es0, r1 = 1.0f / es1;

    SM[(size_t)(row0 + m0) * OUT_F + lane]      = e00 * r0;
    SM[(size_t)(row0 + m0) * OUT_F + 64 + lane] = e01 * r0;
    SM[(size_t)(row0 + m1) * OUT_F + lane]      = e10 * r1;
    SM[(size_t)(row0 + m1) * OUT_F + 64 + lane] = e11 * r1;
}

// ---------------- K2: deterministic segment reduction (no atomics) ----------
// 256 blocks = (batch, class, eighth); each scans 512 rows predicated.
__global__ __launch_bounds__(256) void reduce_kernel(
    const float* __restrict__ SM, const int* __restrict__ Y1, const int* __restrict__ Y2,
    float* __restrict__ pdist, float* __restrict__ pcnt)
{
    __shared__ int lab_s[512];
    __shared__ float sd[2][128];
    __shared__ float cc[2];
    const int b = blockIdx.x;               // 0..255
    const int batch = b >> 7, cls = (b >> 3) & 15, eig = b & 7;
    const int tid = threadIdx.x;
    const int j = tid & 127, half = tid >> 7;
    const int* __restrict__ Y = batch ? Y2 : Y1;

    for (int i = tid; i < 512; i += 256) lab_s[i] = Y[eig * 512 + i];
    __syncthreads();

    const float* __restrict__ base =
        SM + ((size_t)batch * 4096 + (size_t)eig * 512) * OUT_F + j;
    float acc = 0.f;
    int cnt = 0;
    #pragma unroll 8
    for (int r = half; r < 512; r += 2) {
        const bool hit = (lab_s[r] == cls);
        const float v = base[(size_t)r * OUT_F];
        acc += hit ? v : 0.f;
        cnt += hit ? 1 : 0;
    }
    sd[half][j] = acc;
    if (j == 0) cc[half] = (float)cnt;
    __syncthreads();
    if (tid < 128) pdist[(size_t)b * 128 + tid] = sd[0][tid] + sd[1][tid];
    if (tid == 0) pcnt[b] = cc[0] + cc[1];
}

// ---------------- K3: merge partials, class means, KL matrix, loss ----------
__global__ __launch_bounds__(256) void final_kernel(
    const float* __restrict__ pdist, const float* __restrict__ pcnt,
    float* __restrict__ out)
{
    __shared__ float PA[32][NBINS], LA[32][NBINS];
    __shared__ float PB[32][NBINS], LB[32][NBINS];
    __shared__ float J[32][32];
    __shared__ float pls[32];
    __shared__ float cnt[32];
    const int tid = threadIdx.x;

    if (tid < 32) {
        const int batch = tid >> 4, c = tid & 15;
        float s = 0.f;
        #pragma unroll
        for (int q = 0; q < 8; ++q) s += pcnt[batch * 128 + c * 8 + q];
        cnt[tid] = s;
    }
    __syncthreads();

    for (int idx = tid; idx < NCLS * NBINS; idx += 256) {
        const int c = idx >> 7, j = idx & 127;
        float a = 0.f, bsum = 0.f;
        #pragma unroll
        for (int q = 0; q < 8; ++q) {
            a    += pdist[(size_t)(c * 8 + q) * 128 + j];
            bsum += pdist[(size_t)(128 + c * 8 + q) * 128 + j];
        }
        a /= cnt[c];
        bsum /= cnt[16 + c];
        const float mm = 0.5f * (a + bsum);
        PA[c][j] = a;          LA[c][j] = logf(a);
        PA[c + 16][j] = mm;    LA[c + 16][j] = logf(mm);
        PB[c][j] = bsum;       LB[c][j] = logf(bsum);
        PB[c + 16][j] = mm;    LB[c + 16][j] = logf(mm);
    }
    __syncthreads();

    for (int pair = tid; pair < 32 * 32; pair += 256) {
        const int i = pair >> 5, k = pair & 31;
        if (i == k) { J[i][k] = 0.f; continue; }
        float sA = 0.f, sB = 0.f;
        for (int jj = 0; jj < NBINS; ++jj) {
            sA += PA[i][jj] * (LA[i][jj] - LA[k][jj]);
            sB += PB[i][jj] * (LB[i][jj] - LB[k][jj]);
        }
        J[i][k] = 0.5f * (sA + sB);
    }
    __syncthreads();

    if (tid < 32) {
        float den = 0.f;
        for (int k = 0; k < 32; ++k) den += __expf(J[tid][k] * (1.0f / TAUV));
        const float pos = J[tid][(tid + 16) & 31];
        pls[tid] = -(pos * (1.0f / TAUV)) + logf(den);
    }
    __syncthreads();
    if (tid == 0) {
        float s = 0.f;
        for (int i = 0; i < 32; ++i) s += pls[i];
        out[0] = s * (1.0f / 32.0f);
    }
}

extern "C" void kernel_launch(void* const* d_in, const int* in_sizes, int n_in,
                              void* d_out, int out_size, void* d_ws, size_t ws_size,
                              hipStream_t stream)
{
    const float* x1   = (const float*)d_in[0];
    const int*   y1   = (const int*)d_in[1];
    const float* x2   = (const float*)d_in[2];
    const int*   y2   = (const int*)d_in[3];
    const float* W1   = (const float*)d_in[4];
    const float* b1   = (const float*)d_in[5];
    const float* W2   = (const float*)d_in[6];
    const float* b2   = (const float*)d_in[7];
    const float* bins = (const float*)d_in[8];
    float* out = (float*)d_out;

    char* ws = (char*)d_ws;
    float* SM    = (float*)ws;                                    // 8192*128 f32 = 4 MB
    char*  ws2   = ws + (size_t)8192 * 128 * sizeof(float);
    float* pdist = (float*)ws2;                                   // 256*128 f32 = 128 KB
    float* pcnt  = pdist + 256 * 128;                             // 256 f32
    __hip_bfloat16* W1T = (__hip_bfloat16*)(ws2 + 256 * 128 * 4 + 1024); // 128x512 bf16
    __hip_bfloat16* W2T = W1T + (size_t)OUT_F * IN_F;             // 128x128 bf16

    prep_w<<<128, 128, 0, stream>>>(W1, W2, W1T, W2T);
    fused_proj_pdf<<<512, 512, 0, stream>>>(x1, x2, W1T, b1, W2T, b2, bins, SM);
    reduce_kernel<<<256, 256, 0, stream>>>(SM, y1, y2, pdist, pcnt);
    final_kernel<<<1, 256, 0, stream>>>(pdist, pcnt, out);
}

// Round 8
// 65.047 us; speedup vs baseline: 2.7172x; 1.3095x over previous
//
#include <hip/hip_runtime.h>
#include <hip/hip_bf16.h>

#define NROWS 4096
#define IN_F 512
#define OUT_F 128
#define NBINS 128
#define NCLS 16
#define EPSV 1e-8f
#define TAUV 0.1f

// C2EXP = -0.5 / sigma^2 * log2(e),  sigma = 0.2
#define C2EXP (-18.0336880f)
#define M2C   (36.0673760f)   // -2 * C2EXP

#if defined(__has_builtin)
#if __has_builtin(__builtin_amdgcn_exp2f)
#define EXP2F(x) __builtin_amdgcn_exp2f(x)
#else
#define EXP2F(x) exp2f(x)
#endif
#else
#define EXP2F(x) exp2f(x)
#endif

typedef __attribute__((ext_vector_type(8))) short bf16x8;
typedef __attribute__((ext_vector_type(4))) float f32x4;
typedef __attribute__((ext_vector_type(2))) float f32x2;

__device__ __forceinline__ short cvt_bf16(float x) {
    __hip_bfloat16 h = __float2bfloat16(x);
    return *reinterpret_cast<short*>(&h);
}
__device__ __forceinline__ float bf_to_f(unsigned short u) {
    return __uint_as_float((unsigned int)u << 16);
}

// ---------------- K0: transpose + convert weights to bf16 ----------------
__global__ __launch_bounds__(128) void prep_w(
    const float* __restrict__ W1, const float* __restrict__ W2,
    __hip_bfloat16* __restrict__ W1T, __hip_bfloat16* __restrict__ W2T)
{
    const int n = blockIdx.x;      // 0..127 output row (= original col)
    const int t = threadIdx.x;
    for (int k = t; k < IN_F; k += 128)
        W1T[(size_t)n * IN_F + k] = __float2bfloat16(W1[(size_t)k * OUT_F + n]);
    W2T[(size_t)n * OUT_F + t] = __float2bfloat16(W2[(size_t)t * OUT_F + n]);
}

// ---------------- K1: fused MLP projection (MFMA) + normalize + KDE + softmax
// 512 thr = 8 waves; 16 rows/block; 512 blocks. SM output in bf16.
__global__ __launch_bounds__(512) void fused_proj_pdf(
    const float* __restrict__ X1, const float* __restrict__ X2,
    const __hip_bfloat16* __restrict__ W1T, const float* __restrict__ b1,
    const __hip_bfloat16* __restrict__ W2T, const float* __restrict__ b2,
    const float* __restrict__ bins, __hip_bfloat16* __restrict__ SM)
{
    __shared__ __hip_bfloat16 xb[16][IN_F + 8];   // 16.6 KB
    __shared__ __hip_bfloat16 h_lds[16][136];     // 4.3 KB
    __shared__ float pout[16][128];               // 8 KB
    __shared__ f32x2 rowMA[8][2][128];            // 16 KB
    const int tid  = threadIdx.x;
    const int wave = tid >> 6;      // 0..7
    const int lane = tid & 63;
    const int lr   = lane & 15;
    const int kg   = lane >> 4;
    const int row0 = blockIdx.x * 16;
    const float* __restrict__ X = (row0 < NROWS) ? X1 : X2;
    const int xr0 = (row0 < NROWS) ? row0 : row0 - NROWS;
    const int col = wave * 16 + lr;

    // ---- Phase 0: stage X tile (16 x 512 f32 -> bf16 LDS), coalesced ----
    for (int i = tid; i < 16 * 128; i += 512) {
        const int r = i >> 7, c4 = i & 127;
        float4 v = *reinterpret_cast<const float4*>(
            X + (size_t)(xr0 + r) * IN_F + c4 * 4);
        short4 s;
        s.x = cvt_bf16(v.x); s.y = cvt_bf16(v.y);
        s.z = cvt_bf16(v.z); s.w = cvt_bf16(v.w);
        *reinterpret_cast<short4*>(&xb[r][c4 * 4]) = s;
    }
    __syncthreads();

    // ---- GEMM1: (16 x 512) * (512 x 16 per wave) ----
    f32x4 acc = {0.f, 0.f, 0.f, 0.f};
    {
        const __hip_bfloat16* __restrict__ wrow = W1T + (size_t)col * IN_F;
        #pragma unroll 4
        for (int ks = 0; ks < IN_F / 32; ++ks) {
            const int kb = ks * 32 + kg * 8;
            bf16x8 a = *reinterpret_cast<const bf16x8*>(&xb[lr][kb]);
            bf16x8 b = *reinterpret_cast<const bf16x8*>(wrow + kb);
            acc = __builtin_amdgcn_mfma_f32_16x16x32_bf16(a, b, acc, 0, 0, 0);
        }
    }
    {
        const float bb = b1[col];
        #pragma unroll
        for (int q = 0; q < 4; ++q)
            h_lds[kg * 4 + q][col] = __float2bfloat16(fmaxf(acc[q] + bb, 0.f));
    }
    __syncthreads();

    // ---- GEMM2: (16 x 128) * (128 x 16 per wave) ----
    f32x4 c2 = {0.f, 0.f, 0.f, 0.f};
    {
        const __hip_bfloat16* __restrict__ w2row = W2T + (size_t)col * OUT_F;
        #pragma unroll
        for (int ks = 0; ks < OUT_F / 32; ++ks) {
            const int kb = ks * 32 + kg * 8;
            bf16x8 a2 = *reinterpret_cast<const bf16x8*>(&h_lds[lr][kb]);
            bf16x8 b2f = *reinterpret_cast<const bf16x8*>(w2row + kb);
            c2 = __builtin_amdgcn_mfma_f32_16x16x32_bf16(a2, b2f, c2, 0, 0, 0);
        }
    }
    {
        const float cb = b2[col];
        #pragma unroll
        for (int q = 0; q < 4; ++q)
            pout[kg * 4 + q][col] = c2[q] + cb;
    }
    __syncthreads();

    // ---- PDF phase: wave handles rows {2*wave, 2*wave+1}, dual ILP chains ----
    const int m0 = wave * 2, m1 = m0 + 1;
    const float bj0 = bins[lane], bj1 = bins[lane + 64];
    const float B0 = C2EXP * bj0 * bj0, B1 = C2EXP * bj1 * bj1;
    const f32x2 BJ = {bj0, bj1};
    const f32x2 BB = {B0, B1};

    const float p00 = pout[m0][lane], p01 = pout[m0][lane + 64];
    const float p10 = pout[m1][lane], p11 = pout[m1][lane + 64];

    float s0 = p00 * p00 + p01 * p01;
    float s1 = p10 * p10 + p11 * p11;
    #pragma unroll
    for (int off = 32; off; off >>= 1) {
        s0 += __shfl_xor(s0, off);
        s1 += __shfl_xor(s1, off);
    }
    const float i0 = __frsqrt_rn(s0), i1 = __frsqrt_rn(s1);
    const float x00 = p00 * i0, x01 = p01 * i0;
    const float x10 = p10 * i1, x11 = p11 * i1;

    rowMA[wave][0][lane]      = (f32x2){x00 * M2C, C2EXP * x00 * x00};
    rowMA[wave][0][lane + 64] = (f32x2){x01 * M2C, C2EXP * x01 * x01};
    rowMA[wave][1][lane]      = (f32x2){x10 * M2C, C2EXP * x10 * x10};
    rowMA[wave][1][lane + 64] = (f32x2){x11 * M2C, C2EXP * x11 * x11};
    // wave-private LDS, lockstep wave64: compiler orders via lgkmcnt

    const float4* __restrict__ t0b = reinterpret_cast<const float4*>(&rowMA[wave][0][0]);
    const float4* __restrict__ t1b = reinterpret_cast<const float4*>(&rowMA[wave][1][0]);
    f32x2 a0 = {0.f, 0.f}, a1 = {0.f, 0.f};
    #pragma unroll 4
    for (int q = 0; q < 64; ++q) {
        float4 u = t0b[q];
        float4 v = t1b[q];
        f32x2 g;
        g = BJ * u.x + (BB + u.y);
        a0 += (f32x2){EXP2F(g.x), EXP2F(g.y)};
        g = BJ * u.z + (BB + u.w);
        a0 += (f32x2){EXP2F(g.x), EXP2F(g.y)};
        g = BJ * v.x + (BB + v.y);
        a1 += (f32x2){EXP2F(g.x), EXP2F(g.y)};
        g = BJ * v.z + (BB + v.w);
        a1 += (f32x2){EXP2F(g.x), EXP2F(g.y)};
    }

    float pdf00 = a0.x * (1.0f / OUT_F), pdf01 = a0.y * (1.0f / OUT_F);
    float pdf10 = a1.x * (1.0f / OUT_F), pdf11 = a1.y * (1.0f / OUT_F);

    float t0 = pdf00 + pdf01, t1 = pdf10 + pdf11;
    #pragma unroll
    for (int off = 32; off; off >>= 1) {
        t0 += __shfl_xor(t0, off);
        t1 += __shfl_xor(t1, off);
    }
    const float rs0 = 1.0f / (t0 + EPSV), rs1 = 1.0f / (t1 + EPSV);
    pdf00 *= rs0; pdf01 *= rs0; pdf10 *= rs1; pdf11 *= rs1;

    float mx0 = fmaxf(pdf00, pdf01), mx1 = fmaxf(pdf10, pdf11);
    #pragma unroll
    for (int off = 32; off; off >>= 1) {
        mx0 = fmaxf(mx0, __shfl_xor(mx0, off));
        mx1 = fmaxf(mx1, __shfl_xor(mx1, off));
    }
    const float e00 = __expf(pdf00 - mx0), e01 = __expf(pdf01 - mx0);
    const float e10 = __expf(pdf10 - mx1), e11 = __expf(pdf11 - mx1);
    float es0 = e00 + e01, es1 = e10 + e11;
    #pragma unroll
    for (int off = 32; off; off >>= 1) {
        es0 += __shfl_xor(es0, off);
        es1 += __shfl_xor(es1, off);
    }
    const float r0 = 1.0f / es0, r1 = 1.0f / es1;

    SM[(size_t)(row0 + m0) * OUT_F + lane]      = __float2bfloat16(e00 * r0);
    SM[(size_t)(row0 + m0) * OUT_F + 64 + lane] = __float2bfloat16(e01 * r0);
    SM[(size_t)(row0 + m1) * OUT_F + lane]      = __float2bfloat16(e10 * r1);
    SM[(size_t)(row0 + m1) * OUT_F + 64 + lane] = __float2bfloat16(e11 * r1);
}

// ---------------- K2: per-block class partial sums (deterministic) ----------
// 64 blocks = (batch, seg); each owns 128 contiguous rows; reads SM exactly once.
__global__ __launch_bounds__(256) void rowred_kernel(
    const __hip_bfloat16* __restrict__ SM,
    const int* __restrict__ Y1, const int* __restrict__ Y2,
    __hip_bfloat16* __restrict__ pdist, float* __restrict__ pcnt)
{
    __shared__ unsigned short rows_s[128][128];   // 32 KB bf16
    __shared__ int labs[128];
    const int blk = blockIdx.x;           // 0..63
    const int batch = blk >> 5, seg = blk & 31;
    const int tid = threadIdx.x;
    const int* __restrict__ Y = batch ? Y2 : Y1;

    // stage 128x128 bf16 = 32 KB contiguous, uint4 (8 bf16) chunks
    {
        const unsigned short* __restrict__ src =
            (const unsigned short*)SM + ((size_t)batch * 4096 + (size_t)seg * 128) * OUT_F;
        unsigned short* dst = &rows_s[0][0];
        for (int i = tid; i < 128 * 128 / 8; i += 256) {
            *reinterpret_cast<uint4*>(dst + i * 8) =
                *reinterpret_cast<const uint4*>(src + i * 8);
        }
    }
    if (tid < 128) labs[tid] = Y[seg * 128 + tid];
    __syncthreads();

    const int jq = tid & 31;              // j = jq*4 .. +3
    const int c0 = tid >> 5;              // 0..7; handles c0 and c0+8
    f32x4 acc0 = {0.f, 0.f, 0.f, 0.f};
    f32x4 acc1 = {0.f, 0.f, 0.f, 0.f};
    int cnt0 = 0, cnt1 = 0;
    for (int r = 0; r < 128; ++r) {
        ushort4 v = *reinterpret_cast<const ushort4*>(&rows_s[r][jq * 4]);
        const float f0 = bf_to_f(v.x), f1 = bf_to_f(v.y);
        const float f2 = bf_to_f(v.z), f3 = bf_to_f(v.w);
        const int lab = labs[r];
        const float h0 = (lab == c0) ? 1.f : 0.f;
        const float h1 = (lab == c0 + 8) ? 1.f : 0.f;
        acc0.x = fmaf(h0, f0, acc0.x); acc0.y = fmaf(h0, f1, acc0.y);
        acc0.z = fmaf(h0, f2, acc0.z); acc0.w = fmaf(h0, f3, acc0.w);
        acc1.x = fmaf(h1, f0, acc1.x); acc1.y = fmaf(h1, f1, acc1.y);
        acc1.z = fmaf(h1, f2, acc1.z); acc1.w = fmaf(h1, f3, acc1.w);
        cnt0 += (lab == c0);
        cnt1 += (lab == c0 + 8);
    }
    {
        ushort4 o;
        o.x = (unsigned short)cvt_bf16(acc0.x); o.y = (unsigned short)cvt_bf16(acc0.y);
        o.z = (unsigned short)cvt_bf16(acc0.z); o.w = (unsigned short)cvt_bf16(acc0.w);
        *reinterpret_cast<ushort4*>((unsigned short*)pdist +
            ((size_t)blk * NCLS + c0) * NBINS + jq * 4) = o;
        o.x = (unsigned short)cvt_bf16(acc1.x); o.y = (unsigned short)cvt_bf16(acc1.y);
        o.z = (unsigned short)cvt_bf16(acc1.z); o.w = (unsigned short)cvt_bf16(acc1.w);
        *reinterpret_cast<ushort4*>((unsigned short*)pdist +
            ((size_t)blk * NCLS + c0 + 8) * NBINS + jq * 4) = o;
    }
    if (jq == 0) {
        pcnt[blk * NCLS + c0]     = (float)cnt0;
        pcnt[blk * NCLS + c0 + 8] = (float)cnt1;
    }
}

// ---------------- K3: merge partials, class means, KL matrix, loss ----------
__global__ __launch_bounds__(512) void final_kernel(
    const __hip_bfloat16* __restrict__ pdist, const float* __restrict__ pcnt,
    float* __restrict__ out)
{
    __shared__ float PA[32][132], LA[32][132];   // padded rows: no 32-way conflicts
    __shared__ float PB[32][132], LB[32][132];
    __shared__ float J[32][32];
    __shared__ float pls[32];
    __shared__ float cnt[32];
    const int tid = threadIdx.x;
    const unsigned short* __restrict__ pd = (const unsigned short*)pdist;

    if (tid < 32) {
        const int batch = tid >> 4, c = tid & 15;
        float s = 0.f;
        #pragma unroll 8
        for (int seg = 0; seg < 32; ++seg)
            s += pcnt[(batch * 32 + seg) * NCLS + c];
        cnt[tid] = s;
    }
    __syncthreads();

    for (int s = tid; s < NCLS * NBINS; s += 512) {
        const int c = s >> 7, j = s & 127;
        float a = 0.f, b = 0.f;
        #pragma unroll 8
        for (int seg = 0; seg < 32; ++seg) {
            a += bf_to_f(pd[((size_t)(seg) * NCLS + c) * NBINS + j]);
            b += bf_to_f(pd[((size_t)(32 + seg) * NCLS + c) * NBINS + j]);
        }
        a /= cnt[c];
        b /= cnt[16 + c];
        const float mm = 0.5f * (a + b);
        PA[c][j] = a;        LA[c][j] = __logf(a);
        PA[c + 16][j] = mm;  LA[c + 16][j] = __logf(mm);
        PB[c][j] = b;        LB[c][j] = __logf(b);
        PB[c + 16][j] = mm;  LB[c + 16][j] = __logf(mm);
    }
    __syncthreads();

    // KL: 1024 (i,k) pairs, 2 per thread; diag is exactly 0 analytically
    for (int p = tid; p < 32 * 32; p += 512) {
        const int i = p >> 5, k = p & 31;
        float sA = 0.f, sB = 0.f;
        #pragma unroll 4
        for (int jj = 0; jj < NBINS; ++jj) {
            sA += PA[i][jj] * (LA[i][jj] - LA[k][jj]);
            sB += PB[i][jj] * (LB[i][jj] - LB[k][jj]);
        }
        J[i][k] = 0.5f * (sA + sB);
    }
    __syncthreads();

    if (tid < 32) {
        float den = 0.f;
        for (int k = 0; k < 32; ++k) den += __expf(J[tid][k] * (1.0f / TAUV));
        const float pos = J[tid][(tid + 16) & 31];
        pls[tid] = -(pos * (1.0f / TAUV)) + __logf(den);
    }
    __syncthreads();
    if (tid == 0) {
        float s = 0.f;
        for (int i = 0; i < 32; ++i) s += pls[i];
        out[0] = s * (1.0f / 32.0f);
    }
}

extern "C" void kernel_launch(void* const* d_in, const int* in_sizes, int n_in,
                              void* d_out, int out_size, void* d_ws, size_t ws_size,
                              hipStream_t stream)
{
    const float* x1   = (const float*)d_in[0];
    const int*   y1   = (const int*)d_in[1];
    const float* x2   = (const float*)d_in[2];
    const int*   y2   = (const int*)d_in[3];
    const float* W1   = (const float*)d_in[4];
    const float* b1   = (const float*)d_in[5];
    const float* W2   = (const float*)d_in[6];
    const float* b2   = (const float*)d_in[7];
    const float* bins = (const float*)d_in[8];
    float* out = (float*)d_out;

    char* ws = (char*)d_ws;
    __hip_bfloat16* SMb = (__hip_bfloat16*)ws;                    // 8192*128 bf16 = 2 MB
    char* ws2 = ws + (size_t)8192 * 128 * 2;
    __hip_bfloat16* pdist = (__hip_bfloat16*)ws2;                 // 64*16*128 bf16 = 256 KB
    float* pcnt = (float*)(ws2 + (size_t)64 * NCLS * NBINS * 2);  // 64*16 f32
    __hip_bfloat16* W1T = (__hip_bfloat16*)(ws2 + (size_t)64 * NCLS * NBINS * 2 + 8192);
    __hip_bfloat16* W2T = W1T + (size_t)OUT_F * IN_F;

    prep_w<<<128, 128, 0, stream>>>(W1, W2, W1T, W2T);
    fused_proj_pdf<<<512, 512, 0, stream>>>(x1, x2, W1T, b1, W2T, b2, bins, SMb);
    rowred_kernel<<<64, 256, 0, stream>>>(SMb, y1, y2, pdist, pcnt);
    final_kernel<<<1, 512, 0, stream>>>(pdist, pcnt, out);
}

// Round 9
// 58.978 us; speedup vs baseline: 2.9968x; 1.1029x over previous
//
#include <hip/hip_runtime.h>
#include <hip/hip_bf16.h>

#define NROWS 4096
#define IN_F 512
#define OUT_F 128
#define NBINS 128
#define NCLS 16
#define EPSV 1e-8f
#define TAUV 0.1f

// C2EXP = -0.5 / sigma^2 * log2(e),  sigma = 0.2
#define C2EXP (-18.0336880f)
#define M2C   (36.0673760f)   // -2 * C2EXP
#define INV_STEP (12.7f)      // 127 / 10  (bins = linspace(-5,5,128))
#define WRAD 17               // window radius in bins (arg < -36 beyond)

#if defined(__has_builtin)
#if __has_builtin(__builtin_amdgcn_exp2f)
#define EXP2F(x) __builtin_amdgcn_exp2f(x)
#else
#define EXP2F(x) exp2f(x)
#endif
#else
#define EXP2F(x) exp2f(x)
#endif

typedef __attribute__((ext_vector_type(8))) short bf16x8;
typedef __attribute__((ext_vector_type(4))) float f32x4;
typedef __attribute__((ext_vector_type(2))) float f32x2;

__device__ __forceinline__ short cvt_bf16(float x) {
    __hip_bfloat16 h = __float2bfloat16(x);
    return *reinterpret_cast<short*>(&h);
}
__device__ __forceinline__ float bf_to_f(unsigned short u) {
    return __uint_as_float((unsigned int)u << 16);
}

// ---------------- K0: transpose + convert weights to bf16 ----------------
__global__ __launch_bounds__(128) void prep_w(
    const float* __restrict__ W1, const float* __restrict__ W2,
    __hip_bfloat16* __restrict__ W1T, __hip_bfloat16* __restrict__ W2T)
{
    const int n = blockIdx.x;      // 0..127 output row (= original col)
    const int t = threadIdx.x;
    for (int k = t; k < IN_F; k += 128)
        W1T[(size_t)n * IN_F + k] = __float2bfloat16(W1[(size_t)k * OUT_F + n]);
    W2T[(size_t)n * OUT_F + t] = __float2bfloat16(W2[(size_t)t * OUT_F + n]);
}

// ---------------- K1: fused MLP projection (MFMA) + normalize + windowed KDE
//                      + softmax; SM output in bf16.
// 512 thr = 8 waves; 16 rows/block; 512 blocks.
__global__ __launch_bounds__(512) void fused_proj_pdf(
    const float* __restrict__ X1, const float* __restrict__ X2,
    const __hip_bfloat16* __restrict__ W1T, const float* __restrict__ b1,
    const __hip_bfloat16* __restrict__ W2T, const float* __restrict__ b2,
    const float* __restrict__ bins, __hip_bfloat16* __restrict__ SM)
{
    __shared__ __hip_bfloat16 xb[16][IN_F + 8];   // 16.6 KB
    __shared__ __hip_bfloat16 h_lds[16][136];     // 4.3 KB
    __shared__ float pout[16][128];               // 8 KB
    __shared__ f32x2 rowMA[8][2][128];            // 16 KB (m,A) per dim
    __shared__ float bins_s[NBINS];               // 0.5 KB
    const int tid  = threadIdx.x;
    const int wave = tid >> 6;      // 0..7
    const int lane = tid & 63;
    const int lr   = lane & 15;
    const int kg   = lane >> 4;
    const int row0 = blockIdx.x * 16;
    const float* __restrict__ X = (row0 < NROWS) ? X1 : X2;
    const int xr0 = (row0 < NROWS) ? row0 : row0 - NROWS;
    const int col = wave * 16 + lr;

    if (tid < NBINS) bins_s[tid] = bins[tid];

    // ---- Phase 0: stage X tile (16 x 512 f32 -> bf16 LDS), coalesced ----
    for (int i = tid; i < 16 * 128; i += 512) {
        const int r = i >> 7, c4 = i & 127;
        float4 v = *reinterpret_cast<const float4*>(
            X + (size_t)(xr0 + r) * IN_F + c4 * 4);
        short4 s;
        s.x = cvt_bf16(v.x); s.y = cvt_bf16(v.y);
        s.z = cvt_bf16(v.z); s.w = cvt_bf16(v.w);
        *reinterpret_cast<short4*>(&xb[r][c4 * 4]) = s;
    }
    __syncthreads();

    // ---- GEMM1: (16 x 512) * (512 x 16 per wave) ----
    f32x4 acc = {0.f, 0.f, 0.f, 0.f};
    {
        const __hip_bfloat16* __restrict__ wrow = W1T + (size_t)col * IN_F;
        #pragma unroll 4
        for (int ks = 0; ks < IN_F / 32; ++ks) {
            const int kb = ks * 32 + kg * 8;
            bf16x8 a = *reinterpret_cast<const bf16x8*>(&xb[lr][kb]);
            bf16x8 b = *reinterpret_cast<const bf16x8*>(wrow + kb);
            acc = __builtin_amdgcn_mfma_f32_16x16x32_bf16(a, b, acc, 0, 0, 0);
        }
    }
    {
        const float bb = b1[col];
        #pragma unroll
        for (int q = 0; q < 4; ++q)
            h_lds[kg * 4 + q][col] = __float2bfloat16(fmaxf(acc[q] + bb, 0.f));
    }
    __syncthreads();

    // ---- GEMM2: (16 x 128) * (128 x 16 per wave) ----
    f32x4 c2 = {0.f, 0.f, 0.f, 0.f};
    {
        const __hip_bfloat16* __restrict__ w2row = W2T + (size_t)col * OUT_F;
        #pragma unroll
        for (int ks = 0; ks < OUT_F / 32; ++ks) {
            const int kb = ks * 32 + kg * 8;
            bf16x8 a2 = *reinterpret_cast<const bf16x8*>(&h_lds[lr][kb]);
            bf16x8 b2f = *reinterpret_cast<const bf16x8*>(w2row + kb);
            c2 = __builtin_amdgcn_mfma_f32_16x16x32_bf16(a2, b2f, c2, 0, 0, 0);
        }
    }
    {
        const float cb = b2[col];
        #pragma unroll
        for (int q = 0; q < 4; ++q)
            pout[kg * 4 + q][col] = c2[q] + cb;
    }
    __syncthreads();

    // ---- PDF phase: wave handles rows {2*wave, 2*wave+1} ----
    const int m0 = wave * 2, m1 = m0 + 1;

    const float p00 = pout[m0][lane], p01 = pout[m0][lane + 64];
    const float p10 = pout[m1][lane], p11 = pout[m1][lane + 64];

    float s0 = p00 * p00 + p01 * p01;
    float s1 = p10 * p10 + p11 * p11;
    #pragma unroll
    for (int off = 32; off; off >>= 1) {
        s0 += __shfl_xor(s0, off);
        s1 += __shfl_xor(s1, off);
    }
    const float i0 = __frsqrt_rn(s0), i1 = __frsqrt_rn(s1);
    const float x00 = p00 * i0, x01 = p01 * i0;
    const float x10 = p10 * i1, x11 = p11 * i1;

    rowMA[wave][0][lane]      = (f32x2){x00 * M2C, C2EXP * x00 * x00};
    rowMA[wave][0][lane + 64] = (f32x2){x01 * M2C, C2EXP * x01 * x01};
    rowMA[wave][1][lane]      = (f32x2){x10 * M2C, C2EXP * x10 * x10};
    rowMA[wave][1][lane + 64] = (f32x2){x11 * M2C, C2EXP * x11 * x11};
    // wave-private LDS, lockstep wave64: compiler orders via lgkmcnt

    // window over both rows: |x|<=1 guarantees imax-imin <= 61 < 64
    float xlo = fminf(fminf(x00, x01), fminf(x10, x11));
    float xhi = fmaxf(fmaxf(x00, x01), fmaxf(x10, x11));
    #pragma unroll
    for (int off = 32; off; off >>= 1) {
        xlo = fminf(xlo, __shfl_xor(xlo, off));
        xhi = fmaxf(xhi, __shfl_xor(xhi, off));
    }
    int imin = (int)floorf((xlo + 5.0f) * INV_STEP) - WRAD;
    int imax = (int)ceilf ((xhi + 5.0f) * INV_STEP) + WRAD;
    imin = imin < 0 ? 0 : (imin > 127 ? 127 : imin);
    imax = imax > 127 ? 127 : (imax < 0 ? 0 : imax);
    if (imax > imin + 63) imax = imin + 63;   // provably never triggers
    const int nact = imax - imin + 1;
    const int j = imin + lane;
    const bool act = (j <= imax);
    const float bj = bins_s[act ? j : imax];
    const float Bj = C2EXP * bj * bj;

    const float4* __restrict__ t0b = reinterpret_cast<const float4*>(&rowMA[wave][0][0]);
    const float4* __restrict__ t1b = reinterpret_cast<const float4*>(&rowMA[wave][1][0]);
    float acc0 = 0.f, acc1 = 0.f;
    #pragma unroll 8
    for (int q = 0; q < 64; ++q) {
        float4 u = t0b[q];                  // (m_d, A_d, m_{d+1}, A_{d+1}) row0
        float4 v = t1b[q];                  // row1
        acc0 += EXP2F(fmaf(bj, u.x, Bj + u.y));
        acc0 += EXP2F(fmaf(bj, u.z, Bj + u.w));
        acc1 += EXP2F(fmaf(bj, v.x, Bj + v.y));
        acc1 += EXP2F(fmaf(bj, v.z, Bj + v.w));
    }
    float pdf0 = act ? acc0 * (1.0f / OUT_F) : 0.f;
    float pdf1 = act ? acc1 * (1.0f / OUT_F) : 0.f;

    // normalize over all 128 bins (out-of-window bins are exactly 0)
    float t0 = pdf0, t1 = pdf1;
    #pragma unroll
    for (int off = 32; off; off >>= 1) {
        t0 += __shfl_xor(t0, off);
        t1 += __shfl_xor(t1, off);
    }
    pdf0 *= 1.0f / (t0 + EPSV);
    pdf1 *= 1.0f / (t1 + EPSV);

    // softmax max: values >= 0 and zero-bins are 0, so plain max works
    float mx0 = pdf0, mx1 = pdf1;
    #pragma unroll
    for (int off = 32; off; off >>= 1) {
        mx0 = fmaxf(mx0, __shfl_xor(mx0, off));
        mx1 = fmaxf(mx1, __shfl_xor(mx1, off));
    }
    const float q0 = act ? __expf(pdf0 - mx0) : 0.f;
    const float q1 = act ? __expf(pdf1 - mx1) : 0.f;
    const float ez0 = __expf(-mx0), ez1 = __expf(-mx1);
    float es0 = q0, es1 = q1;
    #pragma unroll
    for (int off = 32; off; off >>= 1) {
        es0 += __shfl_xor(es0, off);
        es1 += __shfl_xor(es1, off);
    }
    es0 += (float)(NBINS - nact) * ez0;
    es1 += (float)(NBINS - nact) * ez1;
    const float r0 = 1.0f / es0, r1 = 1.0f / es1;
    const float z0 = ez0 * r0, z1 = ez1 * r1;

    // scatter windowed values to output bins {lane, lane+64}
    const int sa = lane - imin;
    const int sb = lane + 64 - imin;
    const float w0a = __shfl(q0, sa & 63) * r0;
    const float w0b = __shfl(q0, sb & 63) * r0;
    const float w1a = __shfl(q1, sa & 63) * r1;
    const float w1b = __shfl(q1, sb & 63) * r1;
    const bool ina = (unsigned)sa < (unsigned)nact;
    const bool inb = (unsigned)sb < (unsigned)nact;

    SM[(size_t)(row0 + m0) * OUT_F + lane]      = __float2bfloat16(ina ? w0a : z0);
    SM[(size_t)(row0 + m0) * OUT_F + 64 + lane] = __float2bfloat16(inb ? w0b : z0);
    SM[(size_t)(row0 + m1) * OUT_F + lane]      = __float2bfloat16(ina ? w1a : z1);
    SM[(size_t)(row0 + m1) * OUT_F + 64 + lane] = __float2bfloat16(inb ? w1b : z1);
}

// ---------------- K2: per-block class partial sums (deterministic) ----------
// 64 blocks = (batch, seg); each owns 128 contiguous rows; reads SM once.
// pdist layout: [(batch*16 + c)*128 + j]*32 + seg   (bf16)
__global__ __launch_bounds__(256) void rowred_kernel(
    const __hip_bfloat16* __restrict__ SM,
    const int* __restrict__ Y1, const int* __restrict__ Y2,
    __hip_bfloat16* __restrict__ pdist, float* __restrict__ pcnt)
{
    __shared__ unsigned short rows_s[128][128];   // 32 KB bf16
    __shared__ int labs[128];
    const int blk = blockIdx.x;           // 0..63
    const int batch = blk >> 5, seg = blk & 31;
    const int tid = threadIdx.x;
    const int* __restrict__ Y = batch ? Y2 : Y1;

    {
        const unsigned short* __restrict__ src =
            (const unsigned short*)SM + ((size_t)batch * 4096 + (size_t)seg * 128) * OUT_F;
        unsigned short* dst = &rows_s[0][0];
        for (int i = tid; i < 128 * 128 / 8; i += 256) {
            *reinterpret_cast<uint4*>(dst + i * 8) =
                *reinterpret_cast<const uint4*>(src + i * 8);
        }
    }
    if (tid < 128) labs[tid] = Y[seg * 128 + tid];
    __syncthreads();

    const int jq = tid & 31;              // j = jq*4 .. +3
    const int c0 = tid >> 5;              // 0..7; handles c0 and c0+8
    f32x4 acc0 = {0.f, 0.f, 0.f, 0.f};
    f32x4 acc1 = {0.f, 0.f, 0.f, 0.f};
    int cnt0 = 0, cnt1 = 0;
    for (int r = 0; r < 128; ++r) {
        ushort4 v = *reinterpret_cast<const ushort4*>(&rows_s[r][jq * 4]);
        const float f0 = bf_to_f(v.x), f1 = bf_to_f(v.y);
        const float f2 = bf_to_f(v.z), f3 = bf_to_f(v.w);
        const int lab = labs[r];
        const float h0 = (lab == c0) ? 1.f : 0.f;
        const float h1 = (lab == c0 + 8) ? 1.f : 0.f;
        acc0.x = fmaf(h0, f0, acc0.x); acc0.y = fmaf(h0, f1, acc0.y);
        acc0.z = fmaf(h0, f2, acc0.z); acc0.w = fmaf(h0, f3, acc0.w);
        acc1.x = fmaf(h1, f0, acc1.x); acc1.y = fmaf(h1, f1, acc1.y);
        acc1.z = fmaf(h1, f2, acc1.z); acc1.w = fmaf(h1, f3, acc1.w);
        cnt0 += (lab == c0);
        cnt1 += (lab == c0 + 8);
    }
    {
        unsigned short* pd = (unsigned short*)pdist;
        const size_t b0 = ((size_t)(batch * 16 + c0) * 128 + jq * 4) * 32 + seg;
        const size_t b1 = ((size_t)(batch * 16 + c0 + 8) * 128 + jq * 4) * 32 + seg;
        pd[b0 +  0] = (unsigned short)cvt_bf16(acc0.x);
        pd[b0 + 32] = (unsigned short)cvt_bf16(acc0.y);
        pd[b0 + 64] = (unsigned short)cvt_bf16(acc0.z);
        pd[b0 + 96] = (unsigned short)cvt_bf16(acc0.w);
        pd[b1 +  0] = (unsigned short)cvt_bf16(acc1.x);
        pd[b1 + 32] = (unsigned short)cvt_bf16(acc1.y);
        pd[b1 + 64] = (unsigned short)cvt_bf16(acc1.z);
        pd[b1 + 96] = (unsigned short)cvt_bf16(acc1.w);
    }
    if (jq == 0) {
        pcnt[(batch * 16 + c0) * 32 + seg]     = (float)cnt0;
        pcnt[(batch * 16 + c0 + 8) * 32 + seg] = (float)cnt1;
    }
}

// ---------------- K3: merge partials, class means, KL matrix, loss ----------
__global__ __launch_bounds__(512) void final_kernel(
    const __hip_bfloat16* __restrict__ pdist, const float* __restrict__ pcnt,
    float* __restrict__ out)
{
    __shared__ float PA[32][133], LA[32][133];   // pad 133: gcd(133,32)=1
    __shared__ float PB[32][133], LB[32][133];
    __shared__ float J[32][32];
    __shared__ float pls[32];
    __shared__ float cnt[32];
    __shared__ float HA[32], HB[32];
    const int tid = threadIdx.x;
    const unsigned short* __restrict__ pd = (const unsigned short*)pdist;

    if (tid < 32) {
        float s = 0.f;
        #pragma unroll 8
        for (int seg = 0; seg < 32; ++seg) s += pcnt[tid * 32 + seg];
        cnt[tid] = s;
    }

    // merge 32 seg-partials per (bc, j) slot: contiguous 32 bf16 = 4 uint4
    for (int s = tid; s < 32 * NBINS; s += 512) {
        const int bc = s >> 7, jj = s & 127;
        const uint4* base = reinterpret_cast<const uint4*>(pd + (size_t)s * 32);
        float a = 0.f;
        #pragma unroll
        for (int w = 0; w < 4; ++w) {
            uint4 u = base[w];
            const unsigned short* us = (const unsigned short*)&u;
            #pragma unroll
            for (int e = 0; e < 8; ++e) a += bf_to_f(us[e]);
        }
        if (bc < 16) PA[bc][jj] = a;
        else         PB[bc - 16][jj] = a;
    }
    __syncthreads();

    // class means, mixture, logs
    for (int s = tid; s < NCLS * NBINS; s += 512) {
        const int c = s >> 7, jj = s & 127;
        const float a = PA[c][jj] / cnt[c];
        const float b = PB[c][jj] / cnt[16 + c];
        const float mm = 0.5f * (a + b);
        PA[c][jj] = a;        LA[c][jj] = __logf(a);
        PA[c + 16][jj] = mm;  LA[c + 16][jj] = __logf(mm);
        PB[c][jj] = b;        LB[c][jj] = __logf(b);
        PB[c + 16][jj] = mm;  LB[c + 16][jj] = __logf(mm);
    }
    __syncthreads();

    // self terms H[i] = sum_j P[i][j] * L[i][j]
    if (tid < 64) {
        const int i = tid & 31;
        float h = 0.f;
        if (tid < 32) {
            #pragma unroll 4
            for (int jj = 0; jj < NBINS; ++jj) h = fmaf(PA[i][jj], LA[i][jj], h);
            HA[i] = h;
        } else {
            #pragma unroll 4
            for (int jj = 0; jj < NBINS; ++jj) h = fmaf(PB[i][jj], LB[i][jj], h);
            HB[i] = h;
        }
    }
    __syncthreads();

    // KL: J[i][k] = 0.5*((HA[i] - sum PA[i]LA[k]) + (HB[i] - sum PB[i]LB[k]))
    for (int p = tid; p < 32 * 32; p += 512) {
        const int i = p >> 5, k = p & 31;
        if (i == k) { J[i][k] = 0.f; continue; }
        float cA = 0.f, cB = 0.f;
        #pragma unroll 4
        for (int jj = 0; jj < NBINS; ++jj) {
            cA = fmaf(PA[i][jj], LA[k][jj], cA);
            cB = fmaf(PB[i][jj], LB[k][jj], cB);
        }
        J[i][k] = 0.5f * ((HA[i] - cA) + (HB[i] - cB));
    }
    __syncthreads();

    if (tid < 32) {
        float den = 0.f;
        for (int k = 0; k < 32; ++k) den += __expf(J[tid][k] * (1.0f / TAUV));
        const float pos = J[tid][(tid + 16) & 31];
        pls[tid] = -(pos * (1.0f / TAUV)) + __logf(den);
    }
    __syncthreads();
    if (tid == 0) {
        float s = 0.f;
        for (int i = 0; i < 32; ++i) s += pls[i];
        out[0] = s * (1.0f / 32.0f);
    }
}

extern "C" void kernel_launch(void* const* d_in, const int* in_sizes, int n_in,
                              void* d_out, int out_size, void* d_ws, size_t ws_size,
                              hipStream_t stream)
{
    const float* x1   = (const float*)d_in[0];
    const int*   y1   = (const int*)d_in[1];
    const float* x2   = (const float*)d_in[2];
    const int*   y2   = (const int*)d_in[3];
    const float* W1   = (const float*)d_in[4];
    const float* b1   = (const float*)d_in[5];
    const float* W2   = (const float*)d_in[6];
    const float* b2   = (const float*)d_in[7];
    const float* bins = (const float*)d_in[8];
    float* out = (float*)d_out;

    char* ws = (char*)d_ws;
    __hip_bfloat16* SMb = (__hip_bfloat16*)ws;                    // 2 MB
    char* ws2 = ws + (size_t)8192 * 128 * 2;
    __hip_bfloat16* pdist = (__hip_bfloat16*)ws2;                 // 32*128*32 bf16 = 256 KB
    float* pcnt = (float*)(ws2 + (size_t)32 * NBINS * 32 * 2);    // 32*32 f32
    __hip_bfloat16* W1T = (__hip_bfloat16*)(ws2 + (size_t)32 * NBINS * 32 * 2 + 8192);
    __hip_bfloat16* W2T = W1T + (size_t)OUT_F * IN_F;

    prep_w<<<128, 128, 0, stream>>>(W1, W2, W1T, W2T);
    fused_proj_pdf<<<512, 512, 0, stream>>>(x1, x2, W1T, b1, W2T, b2, bins, SMb);
    rowred_kernel<<<64, 256, 0, stream>>>(SMb, y1, y2, pdist, pcnt);
    final_kernel<<<1, 512, 0, stream>>>(pdist, pcnt, out);
}